// Round 12
// baseline (325.350 us; speedup 1.0000x reference)
//
#include <hip/hip_runtime.h>

#define DEV __device__ __forceinline__
typedef unsigned short u16;
typedef __bf16 bf16x8 __attribute__((ext_vector_type(8)));
typedef float f32x4 __attribute__((ext_vector_type(4)));
typedef float f32x16 __attribute__((ext_vector_type(16)));

DEV u16 f2bf(float f) {                      // RNE f32 -> bf16
  unsigned u = __float_as_uint(f);
  u += 0x7FFF + ((u >> 16) & 1);
  return (u16)(u >> 16);
}

// ---------------- geometry ----------------
// x    [64,3,125,125] fp32
// xp   [64,3,129,128] fp32 zero-padded
// z1t  [64,63,64,32]  bf16
// z2   [64,64,32,32]  fp32
// z3   [64,64,32,32]  fp32  + z3h/z3l [65536][64] bf16
// e_t  [64,32,32,64]  bf16  pixel-major
// h1t  [64,64,64,64]  bf16  pixel-major
// h2t  [64,128,128,32] bf16 pixel-major
// xr   [64,3,125,125] fp32
//
// 32x32x16 MFMA layouts: A[m=lane&31][k=(lane>>5)*8+j],
// B[k=(lane>>5)*8+j][n=lane&31], D col=lane&31, row=(reg&3)+8*(reg>>2)+4*(lane>>5)

// ---------------- prep ----------------
// wt1g [kt9][s4][cg2][lane64][8] bf16   convT1 B-frags (32x32, K=16 slices)
// wt2g [kt9][s4][lane64][8] bf16        convT2 B-frags (32x32)
__global__ __launch_bounds__(256) void k_prep(
    const float* __restrict__ ew1, const float* __restrict__ ew2,
    const float* __restrict__ ew3, const float* __restrict__ dw1,
    const float* __restrict__ dw2, const float* __restrict__ dw3,
    const float* __restrict__ cb,
    float* __restrict__ wc1p, float* __restrict__ wc3p,
    u16* __restrict__ w3f, float* __restrict__ c2,
    u16* __restrict__ w2f, u16* __restrict__ wt1g, u16* __restrict__ wt2g,
    u16* __restrict__ cbf) {
  int i = blockIdx.x * 256 + threadIdx.x;
  if (i < 864) {
    int cl = i & 7; int t = i >> 3; int tap = t % 9; t /= 9; int ci = t % 3; int cog = t / 3;
    wc1p[i] = ew1[((cog * 8 + cl) * 3 + ci) * 9 + tap];
  } else if (i < 4960) {
    int j = i - 864; int cl = j & 7; int t = j >> 3; int ci = t & 63; int cog = t >> 6;
    wc3p[j] = ew3[(cog * 8 + cl) * 64 + ci];
  } else if (i < 9056) {
    int j = i - 4960;                       // [hl][tp][lane][8]
    int jj = j & 7; int lane = (j >> 3) & 63; int tp = (j >> 9) & 3; int hl = j >> 11;
    int kh = tp >> 1, kw = tp & 1;
    int ci = ((lane >> 4) << 3) + jj; int co = lane & 15;
    float wv = (co < 3) ? dw3[((ci * 3 + co) * 2 + kh) * 2 + kw] : 0.f;
    u16 hi = f2bf(wv);
    if (hl == 0) w3f[j] = hi;
    else         w3f[j] = f2bf(wv - __uint_as_float((unsigned)hi << 16));
  } else if (i < 9568) {
    int k = i - 9056;
    const float4* c4 = (const float4*)(cb + (k << 6));
    float s = 0.f;
    #pragma unroll
    for (int q = 0; q < 16; ++q) { float4 v = c4[q]; s += v.x*v.x + v.y*v.y + v.z*v.z + v.w*v.w; }
    c2[k] = s;
  } else if (i < 28000) {
    int j = i - 9568;                       // [kt][nf][lane][8]
    int jj = j & 7; int lane = (j >> 3) & 63; int nf = (j >> 9) & 3; int kt = j >> 11;
    int kh = kt / 3, kw = kt % 3;
    int ci = ((lane >> 4) << 3) + jj; int co = (nf << 4) + (lane & 15);
    w2f[j] = f2bf(ew2[((co * 32 + ci) * 3 + kh) * 3 + kw]);
  } else if (i < 64864) {
    int j = i - 28000;                      // wt1g [kt][s][cg][lane][8]
    int jj = j & 7; int lane = (j >> 3) & 63; int cg = (j >> 9) & 1; int s = (j >> 10) & 3; int kt = j >> 12;
    int ci = s * 16 + ((lane >> 5) << 3) + jj;
    int co = cg * 32 + (lane & 31);
    wt1g[j] = f2bf(dw1[(ci * 64 + co) * 9 + kt]);
  } else if (i < 83296) {
    int j = i - 64864;                      // wt2g [kt][s][lane][8]
    int jj = j & 7; int lane = (j >> 3) & 63; int s = (j >> 9) & 3; int kt = j >> 11;
    int ci = s * 16 + ((lane >> 5) << 3) + jj;
    int co = lane & 31;
    wt2g[j] = f2bf(dw2[(ci * 32 + co) * 9 + kt]);
  } else if (i < 148832) {
    int j = i - 83296;                      // [hl][ks][nt][lane][8]
    int jj = j & 7; int lane = (j >> 3) & 63; int nt = (j >> 9) & 31; int ks = (j >> 14) & 1; int hl = j >> 15;
    int ci = (ks << 5) + ((lane >> 4) << 3) + jj;
    int code = (nt << 4) + (lane & 15);
    float v = cb[(code << 6) + ci];
    u16 hi = f2bf(v);
    cbf[j] = hl ? f2bf(v - __uint_as_float((unsigned)hi << 16)) : hi;
  }
}

// ---------------- pad: x -> xp [64*3][129][128], zero borders ----------------
__global__ __launch_bounds__(256) void k_pad(
    const float* __restrict__ x, float* __restrict__ xp) {
  int idx = blockIdx.x * 256 + threadIdx.x;
  int c4 = idx & 31;
  int r  = (idx >> 5) % 129;
  int cbp = (idx >> 5) / 129;
  int ih = r - 1;
  float4 v = make_float4(0.f, 0.f, 0.f, 0.f);
  if ((unsigned)ih < 125u) {
    const float* rp = x + (cbp * 125 + ih) * 125;
    int iw0 = c4 * 4 - 1;
    if (iw0 >= 0)        v.x = rp[iw0];
    if (iw0 + 1 < 125)   v.y = rp[iw0 + 1];
    if (iw0 + 2 < 125)   v.z = rp[iw0 + 2];
    if (iw0 + 3 < 125)   v.w = rp[iw0 + 3];
  }
  *(float4*)(xp + (cbp * 129 + r) * 128 + c4 * 4) = v;
}

// ---------------- conv1: padded input, all-co blocks, LDS wide stores ----------------
__global__ __launch_bounds__(256) void k_conv1(
    const float* __restrict__ xp, const float* __restrict__ wp,
    const float* __restrict__ bias, u16* __restrict__ z1t) {
  __shared__ u16 st[256 * 34];
  int t = threadIdx.x;
  int slab = blockIdx.x & 15, b = blockIdx.x >> 4;   // grid 1024
  int tx = t & 15, ty = (t >> 4) & 3, cg = t >> 6;
  int oh = slab * 4 + ty;
  int co0 = cg * 8;
  const float* wcg = wp + cg * 216;
  float acc[8][4];
  #pragma unroll
  for (int c = 0; c < 8; ++c) {
    float bv = bias[co0 + c];
    #pragma unroll
    for (int s = 0; s < 4; ++s) acc[c][s] = bv;
  }
  #pragma unroll
  for (int ci = 0; ci < 3; ++ci) {
    #pragma unroll
    for (int kh = 0; kh < 3; ++kh) {
      const float* rp = xp + ((b * 3 + ci) * 129 + (2 * oh + kh)) * 128 + 8 * tx;
      float4 qa = *(const float4*)rp;
      float4 qb = *(const float4*)(rp + 4);
      float v8 = rp[8];
      float v[9] = {qa.x, qa.y, qa.z, qa.w, qb.x, qb.y, qb.z, qb.w, v8};
      #pragma unroll
      for (int kw = 0; kw < 3; ++kw) {
        const float* wq = wcg + (ci * 9 + kh * 3 + kw) * 8;
        float4 wa = *(const float4*)wq;
        float4 wb = *(const float4*)(wq + 4);
        float w8[8] = {wa.x, wa.y, wa.z, wa.w, wb.x, wb.y, wb.z, wb.w};
        #pragma unroll
        for (int s = 0; s < 4; ++s) {
          float in = v[2 * s + kw];
          #pragma unroll
          for (int c = 0; c < 8; ++c) acc[c][s] = fmaf(in, w8[c], acc[c][s]);
        }
      }
    }
  }
  #pragma unroll
  for (int s = 0; s < 4; ++s) {
    bool wok = (tx * 4 + s) < 63;
    unsigned p0 = 0, p1 = 0, p2 = 0, p3 = 0;
    if (wok) {
      p0 = f2bf(fmaxf(acc[0][s], 0.f)) | ((unsigned)f2bf(fmaxf(acc[1][s], 0.f)) << 16);
      p1 = f2bf(fmaxf(acc[2][s], 0.f)) | ((unsigned)f2bf(fmaxf(acc[3][s], 0.f)) << 16);
      p2 = f2bf(fmaxf(acc[4][s], 0.f)) | ((unsigned)f2bf(fmaxf(acc[5][s], 0.f)) << 16);
      p3 = f2bf(fmaxf(acc[6][s], 0.f)) | ((unsigned)f2bf(fmaxf(acc[7][s], 0.f)) << 16);
    }
    int lpix = tx * 16 + ty * 4 + s;
    *(uint4*)&st[lpix * 34 + co0] = make_uint4(p0, p1, p2, p3);
  }
  __syncthreads();
  {
    int p = t;
    int ow = (p >> 4) * 4 + (p & 3);
    int ohl = (p >> 2) & 3;
    int oho = slab * 4 + ohl;
    if (oho < 63) {
      const u16* lp = &st[p * 34];
      uint4 a0 = *(const uint4*)(lp);
      uint4 a1 = *(const uint4*)(lp + 8);
      uint4 a2 = *(const uint4*)(lp + 16);
      uint4 a3 = *(const uint4*)(lp + 24);
      uint4* gp = (uint4*)(z1t + ((b * 63 + oho) * 64 + ow) * 32);
      gp[0] = a0; gp[1] = a1; gp[2] = a2; gp[3] = a3;
    }
  }
}

// ---------------- conv2: MFMA, block=(b,oh), waves=(xt2, ch2) ----------------
__global__ __launch_bounds__(256) void k_conv2(
    const u16* __restrict__ z1t, const u16* __restrict__ wf,
    const float* __restrict__ bias, float* __restrict__ z2) {
  int t = threadIdx.x;
  int lane = t & 63, wv = t >> 6;
  int n = lane & 15, q = lane >> 4;
  int oh = blockIdx.x & 31, b = blockIdx.x >> 5;   // grid 2048
  int xt = wv & 1, ch = wv >> 1;
  int xA = xt * 16 + n;
  f32x4 acc[2] = {{0,0,0,0},{0,0,0,0}};
  #pragma unroll
  for (int kh = 0; kh < 3; ++kh) {
    int ih = 2 * oh - 1 + kh;
    bool yok = (unsigned)ih < 63u;
    #pragma unroll
    for (int kw = 0; kw < 3; ++kw) {
      int iw = 2 * xA - 1 + kw;
      bool ok = yok && (iw >= 0);
      bf16x8 a = {};
      if (ok) a = *(const bf16x8*)(z1t + ((b * 63 + ih) * 64 + iw) * 32 + q * 8);
      int kt = kh * 3 + kw;
      const u16* wb = wf + ((kt << 2) + (ch << 1)) * 512 + lane * 8;
      bf16x8 b0 = *(const bf16x8*)wb;
      bf16x8 b1 = *(const bf16x8*)(wb + 512);
      acc[0] = __builtin_amdgcn_mfma_f32_16x16x32_bf16(a, b0, acc[0], 0, 0, 0);
      acc[1] = __builtin_amdgcn_mfma_f32_16x16x32_bf16(a, b1, acc[1], 0, 0, 0);
    }
  }
  #pragma unroll
  for (int j = 0; j < 2; ++j) {
    int co = ((ch << 1) + j) * 16 + n;
    float bv = bias[co];
    float4 rv = make_float4(fmaxf(acc[j][0] + bv, 0.f), fmaxf(acc[j][1] + bv, 0.f),
                            fmaxf(acc[j][2] + bv, 0.f), fmaxf(acc[j][3] + bv, 0.f));
    *(float4*)(z2 + ((b * 64 + co) * 32 + oh) * 32 + xt * 16 + q * 4) = rv;
  }
}

// ---------------- conv3 (1x1): fp32, + LDS transpose to pixel-major hi/lo ----------------
__global__ __launch_bounds__(256) void k_conv3(
    const float* __restrict__ in, const float* __restrict__ wp,
    const float* __restrict__ bias, float* __restrict__ z3,
    u16* __restrict__ z3h, u16* __restrict__ z3l) {
  __shared__ u16 lh[128 * 72];
  __shared__ u16 ll[128 * 72];
  int t = threadIdx.x;
  int pxg = blockIdx.x & 7; int b = blockIdx.x >> 3;   // grid 512
  int pxi = t & 31, cog = t >> 5;
  int px0 = pxg * 128 + pxi * 4;
  const float* wcg = wp + cog * 512;
  int co0 = cog * 8;
  float acc[8][4];
  #pragma unroll
  for (int c = 0; c < 8; ++c) {
    float bv = bias[co0 + c];
    #pragma unroll
    for (int s = 0; s < 4; ++s) acc[c][s] = bv;
  }
  const float* ip = in + (b << 16) + px0;
  for (int ci = 0; ci < 64; ++ci) {
    float4 v = *(const float4*)(ip + (ci << 10));
    float4 wa = *(const float4*)(wcg + ci * 8);
    float4 wb = *(const float4*)(wcg + ci * 8 + 4);
    float w8[8] = {wa.x, wa.y, wa.z, wa.w, wb.x, wb.y, wb.z, wb.w};
    #pragma unroll
    for (int c = 0; c < 8; ++c) {
      acc[c][0] = fmaf(v.x, w8[c], acc[c][0]);
      acc[c][1] = fmaf(v.y, w8[c], acc[c][1]);
      acc[c][2] = fmaf(v.z, w8[c], acc[c][2]);
      acc[c][3] = fmaf(v.w, w8[c], acc[c][3]);
    }
  }
  float* op = z3 + ((b << 6) + co0) * 1024 + px0;
  #pragma unroll
  for (int c = 0; c < 8; ++c)
    *(float4*)(op + (c << 10)) = make_float4(acc[c][0], acc[c][1], acc[c][2], acc[c][3]);
  #pragma unroll
  for (int s = 0; s < 4; ++s) {
    unsigned h[4], l[4];
    #pragma unroll
    for (int g = 0; g < 4; ++g) {
      float v0 = acc[2 * g][s], v1 = acc[2 * g + 1][s];
      u16 h0 = f2bf(v0), h1 = f2bf(v1);
      u16 l0 = f2bf(v0 - __uint_as_float((unsigned)h0 << 16));
      u16 l1 = f2bf(v1 - __uint_as_float((unsigned)h1 << 16));
      h[g] = h0 | ((unsigned)h1 << 16);
      l[g] = l0 | ((unsigned)l1 << 16);
    }
    int la = (pxi * 4 + s) * 72 + co0;
    *(uint4*)&lh[la] = make_uint4(h[0], h[1], h[2], h[3]);
    *(uint4*)&ll[la] = make_uint4(l[0], l[1], l[2], l[3]);
  }
  __syncthreads();
  {
    int p = t >> 1, half = t & 1;
    int la = p * 72 + half * 32;
    uint4 h0 = *(uint4*)&lh[la],      h1 = *(uint4*)&lh[la + 8];
    uint4 h2 = *(uint4*)&lh[la + 16], h3 = *(uint4*)&lh[la + 24];
    uint4 l0 = *(uint4*)&ll[la],      l1 = *(uint4*)&ll[la + 8];
    uint4 l2 = *(uint4*)&ll[la + 16], l3 = *(uint4*)&ll[la + 24];
    long gp = ((long)b * 1024 + pxg * 128 + p) * 64 + half * 32;
    uint4* oh = (uint4*)(z3h + gp);
    uint4* ol = (uint4*)(z3l + gp);
    oh[0] = h0; oh[1] = h1; oh[2] = h2; oh[3] = h3;
    ol[0] = l0; ol[1] = l1; ol[2] = l2; ol[3] = l3;
  }
}

// ---------------- VQ argmin: MFMA hi/lo, 64 px/wave x 512 codes ----------------
__global__ __launch_bounds__(256) void k_vqp(
    const u16* __restrict__ z3h, const u16* __restrict__ z3l,
    const u16* __restrict__ cbf, const float* __restrict__ c2v,
    int* __restrict__ idxb) {
  int t = threadIdx.x;
  int lane = t & 63, wv = t >> 6;
  int n = lane & 15, q = lane >> 4;
  int p0 = (blockIdx.x * 4 + wv) * 64;               // grid 256
  bf16x8 Ah[4][2], Al[4][2];
  #pragma unroll
  for (int mt = 0; mt < 4; ++mt) {
    const u16* ap = z3h + (p0 + mt * 16 + n) * 64 + q * 8;
    const u16* al = z3l + (p0 + mt * 16 + n) * 64 + q * 8;
    Ah[mt][0] = *(const bf16x8*)ap;  Ah[mt][1] = *(const bf16x8*)(ap + 32);
    Al[mt][0] = *(const bf16x8*)al;  Al[mt][1] = *(const bf16x8*)(al + 32);
  }
  float bs[4][4]; int bix[4][4];
  #pragma unroll
  for (int mt = 0; mt < 4; ++mt)
    #pragma unroll
    for (int r = 0; r < 4; ++r) { bs[mt][r] = 3.4e38f; bix[mt][r] = 0; }
  for (int nt = 0; nt < 32; ++nt) {
    const u16* bp = cbf + lane * 8;
    bf16x8 Bh0 = *(const bf16x8*)(bp + (nt << 9));
    bf16x8 Bh1 = *(const bf16x8*)(bp + ((32 + nt) << 9));
    bf16x8 Bl0 = *(const bf16x8*)(bp + ((64 + nt) << 9));
    bf16x8 Bl1 = *(const bf16x8*)(bp + ((96 + nt) << 9));
    float c2 = c2v[(nt << 4) + n];
    #pragma unroll
    for (int mt = 0; mt < 4; ++mt) {
      f32x4 acc = {0.f, 0.f, 0.f, 0.f};
      acc = __builtin_amdgcn_mfma_f32_16x16x32_bf16(Ah[mt][0], Bh0, acc, 0, 0, 0);
      acc = __builtin_amdgcn_mfma_f32_16x16x32_bf16(Ah[mt][1], Bh1, acc, 0, 0, 0);
      acc = __builtin_amdgcn_mfma_f32_16x16x32_bf16(Al[mt][0], Bh0, acc, 0, 0, 0);
      acc = __builtin_amdgcn_mfma_f32_16x16x32_bf16(Al[mt][1], Bh1, acc, 0, 0, 0);
      acc = __builtin_amdgcn_mfma_f32_16x16x32_bf16(Ah[mt][0], Bl0, acc, 0, 0, 0);
      acc = __builtin_amdgcn_mfma_f32_16x16x32_bf16(Ah[mt][1], Bl1, acc, 0, 0, 0);
      int idx = (nt << 4) + n;
      #pragma unroll
      for (int r = 0; r < 4; ++r) {
        float sc = fmaf(-2.f, acc[r], c2);
        if (sc < bs[mt][r]) { bs[mt][r] = sc; bix[mt][r] = idx; }
      }
    }
  }
  #pragma unroll
  for (int off = 8; off > 0; off >>= 1) {
    #pragma unroll
    for (int mt = 0; mt < 4; ++mt)
      #pragma unroll
      for (int r = 0; r < 4; ++r) {
        float os = __shfl_xor(bs[mt][r], off, 16);
        int oi = __shfl_xor(bix[mt][r], off, 16);
        if (os < bs[mt][r] || (os == bs[mt][r] && oi < bix[mt][r])) {
          bs[mt][r] = os; bix[mt][r] = oi;
        }
      }
  }
  if (n == 0) {
    #pragma unroll
    for (int mt = 0; mt < 4; ++mt)
      #pragma unroll
      for (int r = 0; r < 4; ++r)
        idxb[p0 + mt * 16 + q * 4 + r] = bix[mt][r];
  }
}

// ---------------- VQ finalize: gather, write e_t bf16, loss ----------------
__global__ __launch_bounds__(256) void k_vqf(
    const float* __restrict__ z3, const float* __restrict__ cb,
    const int* __restrict__ idxb, u16* __restrict__ et,
    float* __restrict__ acc) {
  int n = blockIdx.x * 256 + threadIdx.x;  // 65536
  int bi = idxb[n];
  int b = n >> 10, hw = n & 1023;
  const float* zp = z3 + (b << 16) + hw;
  uint2* ep = (uint2*)(et + (n << 6));
  const float4* cq = (const float4*)(cb + (bi << 6));
  float lsum = 0.f;
  #pragma unroll
  for (int i = 0; i < 16; ++i) {
    float4 c = cq[i];
    float zv, df;
    zv = zp[(4*i+0) << 10]; df = c.x - zv; lsum = fmaf(df, df, lsum);
    zv = zp[(4*i+1) << 10]; df = c.y - zv; lsum = fmaf(df, df, lsum);
    zv = zp[(4*i+2) << 10]; df = c.z - zv; lsum = fmaf(df, df, lsum);
    zv = zp[(4*i+3) << 10]; df = c.w - zv; lsum = fmaf(df, df, lsum);
    ep[i] = make_uint2(f2bf(c.x) | ((unsigned)f2bf(c.y) << 16),
                       f2bf(c.z) | ((unsigned)f2bf(c.w) << 16));
  }
  __shared__ float red[256];
  red[threadIdx.x] = lsum; __syncthreads();
  #pragma unroll
  for (int s = 128; s > 0; s >>= 1) {
    if (threadIdx.x < s) red[threadIdx.x] += red[threadIdx.x + s];
    __syncthreads();
  }
  if (threadIdx.x == 0) atomicAdd(acc + 0, red[0]);
}

// ---------------- convT1: 32x32 MFMA, 2 y-pairs/block, LDS wide stores ----------------
// waves = (yw2, cog2). wave covers 32 input px (full row) x 32 co x 2 out rows.
__global__ __launch_bounds__(256) void k_convT1(
    const u16* __restrict__ et, const u16* __restrict__ wf,
    const float* __restrict__ bias, u16* __restrict__ h1t) {
  __shared__ u16 st[4][64 * 66];
  int t = threadIdx.x;
  int lane = t & 63, wv = t >> 6;
  int yw = wv & 1, cog = wv >> 1;
  int yg = blockIdx.x & 15, b = blockIdx.x >> 4;   // grid 1024
  int y = yg * 2 + yw;
  int ml = lane & 31, half = lane >> 5;
  int co = cog * 32 + ml;
  float bv = bias[co];
  bf16x8 A[2][2][4];
  #pragma unroll
  for (int r = 0; r < 2; ++r)
    #pragma unroll
    for (int sh = 0; sh < 2; ++sh)
      #pragma unroll
      for (int s = 0; s < 4; ++s) A[r][sh][s] = bf16x8{};
  {
    const u16* base = et + (((b * 32 + y) * 32) << 6) + half * 8;
    #pragma unroll
    for (int s = 0; s < 4; ++s) A[0][0][s] = *(const bf16x8*)(base + (ml << 6) + s * 16);
    if (ml + 1 < 32) {
      #pragma unroll
      for (int s = 0; s < 4; ++s) A[0][1][s] = *(const bf16x8*)(base + ((ml + 1) << 6) + s * 16);
    }
    if (y + 1 < 32) {
      const u16* base1 = base + (32 << 6);
      #pragma unroll
      for (int s = 0; s < 4; ++s) A[1][0][s] = *(const bf16x8*)(base1 + (ml << 6) + s * 16);
      if (ml + 1 < 32) {
        #pragma unroll
        for (int s = 0; s < 4; ++s) A[1][1][s] = *(const bf16x8*)(base1 + ((ml + 1) << 6) + s * 16);
      }
    }
  }
  f32x16 accE[2] = {}, accO[2] = {};
  #pragma unroll
  for (int kw = 0; kw < 3; ++kw) {
    int pwi = (kw == 1) ? 0 : 1;
    int sh = (kw == 0) ? 1 : 0;
    #pragma unroll
    for (int s = 0; s < 4; ++s) {
      bf16x8 a0 = A[0][sh][s], a1 = A[1][sh][s];
      const u16* wE  = wf + ((((3 + kw) << 2) + s) << 10) + (cog << 9) + lane * 8;
      const u16* wO0 = wf + (((kw << 2) + s) << 10) + (cog << 9) + lane * 8;
      const u16* wO2 = wf + ((((6 + kw) << 2) + s) << 10) + (cog << 9) + lane * 8;
      accE[pwi] = __builtin_amdgcn_mfma_f32_32x32x16_bf16(a0, *(const bf16x8*)wE,  accE[pwi], 0, 0, 0);
      accO[pwi] = __builtin_amdgcn_mfma_f32_32x32x16_bf16(a1, *(const bf16x8*)wO0, accO[pwi], 0, 0, 0);
      accO[pwi] = __builtin_amdgcn_mfma_f32_32x32x16_bf16(a0, *(const bf16x8*)wO2, accO[pwi], 0, 0, 0);
    }
  }
  #pragma unroll
  for (int pw = 0; pw < 2; ++pw)
    #pragma unroll
    for (int reg = 0; reg < 16; ++reg) {
      int m_l = (reg & 3) + ((reg >> 2) << 3) + (half << 2);
      int ow = 2 * m_l + pw;
      st[yw * 2 + 0][ow * 66 + co] = f2bf(fmaxf(accE[pw][reg] + bv, 0.f));
      st[yw * 2 + 1][ow * 66 + co] = f2bf(fmaxf(accO[pw][reg] + bv, 0.f));
    }
  __syncthreads();
  {
    int row = t >> 6, ow = t & 63;
    const u16* lp = &st[row][ow * 66];
    uint4* gp = (uint4*)(h1t + (((b * 64 + yg * 4 + row) * 64 + ow) << 6));
    #pragma unroll
    for (int g = 0; g < 8; ++g) gp[g] = *(const uint4*)(lp + g * 8);
  }
}

// ---------------- convT2: 32x32 MFMA, 2 y-pairs/block, LDS wide stores ----------------
// waves = (yw2, xt2). wave covers 32 input px x 32 co x 2 out rows.
__global__ __launch_bounds__(256) void k_convT2(
    const u16* __restrict__ h1t, const u16* __restrict__ wf,
    const float* __restrict__ bias, u16* __restrict__ h2t) {
  __shared__ u16 st[4][128 * 34];
  int t = threadIdx.x;
  int lane = t & 63, wv = t >> 6;
  int yw = wv & 1, xt = wv >> 1;
  int yg = blockIdx.x & 31, b = blockIdx.x >> 5;   // grid 2048
  int y = yg * 2 + yw;
  int ml = lane & 31, half = lane >> 5;
  int m = xt * 32 + ml;
  int co = ml;
  float bv = bias[co];
  bf16x8 A[2][2][4];
  #pragma unroll
  for (int r = 0; r < 2; ++r)
    #pragma unroll
    for (int sh = 0; sh < 2; ++sh)
      #pragma unroll
      for (int s = 0; s < 4; ++s) A[r][sh][s] = bf16x8{};
  {
    const u16* base = h1t + (((b * 64 + y) * 64) << 6) + half * 8;
    #pragma unroll
    for (int s = 0; s < 4; ++s) A[0][0][s] = *(const bf16x8*)(base + (m << 6) + s * 16);
    if (m + 1 < 64) {
      #pragma unroll
      for (int s = 0; s < 4; ++s) A[0][1][s] = *(const bf16x8*)(base + ((m + 1) << 6) + s * 16);
    }
    if (y + 1 < 64) {
      const u16* base1 = base + (64 << 6);
      #pragma unroll
      for (int s = 0; s < 4; ++s) A[1][0][s] = *(const bf16x8*)(base1 + (m << 6) + s * 16);
      if (m + 1 < 64) {
        #pragma unroll
        for (int s = 0; s < 4; ++s) A[1][1][s] = *(const bf16x8*)(base1 + ((m + 1) << 6) + s * 16);
      }
    }
  }
  f32x16 accE[2] = {}, accO[2] = {};
  #pragma unroll
  for (int kw = 0; kw < 3; ++kw) {
    int pwi = (kw == 1) ? 0 : 1;
    int sh = (kw == 0) ? 1 : 0;
    #pragma unroll
    for (int s = 0; s < 4; ++s) {
      bf16x8 a0 = A[0][sh][s], a1 = A[1][sh][s];
      const u16* wE  = wf + ((((3 + kw) << 2) + s) << 9) + lane * 8;
      const u16* wO0 = wf + (((kw << 2) + s) << 9) + lane * 8;
      const u16* wO2 = wf + ((((6 + kw) << 2) + s) << 9) + lane * 8;
      accE[pwi] = __builtin_amdgcn_mfma_f32_32x32x16_bf16(a0, *(const bf16x8*)wE,  accE[pwi], 0, 0, 0);
      accO[pwi] = __builtin_amdgcn_mfma_f32_32x32x16_bf16(a1, *(const bf16x8*)wO0, accO[pwi], 0, 0, 0);
      accO[pwi] = __builtin_amdgcn_mfma_f32_32x32x16_bf16(a0, *(const bf16x8*)wO2, accO[pwi], 0, 0, 0);
    }
  }
  #pragma unroll
  for (int pw = 0; pw < 2; ++pw)
    #pragma unroll
    for (int reg = 0; reg < 16; ++reg) {
      int m_l = (reg & 3) + ((reg >> 2) << 3) + (half << 2);
      int ow = 2 * (xt * 32 + m_l) + pw;
      st[yw * 2 + 0][ow * 34 + co] = f2bf(fmaxf(accE[pw][reg] + bv, 0.f));
      st[yw * 2 + 1][ow * 34 + co] = f2bf(fmaxf(accO[pw][reg] + bv, 0.f));
    }
  __syncthreads();
  #pragma unroll
  for (int l2 = 0; l2 < 2; ++l2) {
    int idx = t * 2 + l2;
    int row = idx >> 7, ow = idx & 127;
    const u16* lp = &st[row][ow * 34];
    uint4* gp = (uint4*)(h2t + (((b * 128 + yg * 4 + row) * 128 + ow) << 5));
    gp[0] = *(const uint4*)(lp);
    gp[1] = *(const uint4*)(lp + 8);
    gp[2] = *(const uint4*)(lp + 16);
    gp[3] = *(const uint4*)(lp + 24);
  }
}

// ---------------- convT3 + recon loss: MFMA, per-block partial sums ----------------
__global__ __launch_bounds__(256) void k_convT3(
    const u16* __restrict__ h2t, const u16* __restrict__ w3f,
    const float* __restrict__ bias, const float* __restrict__ x,
    float* __restrict__ xr, float* __restrict__ psum) {
  int t = threadIdx.x;
  int lane = t & 63, wv = t >> 6;
  int n = lane & 15, q = lane >> 4;
  int oh = blockIdx.x % 125, b = blockIdx.x / 125;   // grid 8000
  const u16* wbp = w3f + lane * 8;
  bf16x8 Bh0 = *(const bf16x8*)(wbp);
  bf16x8 Bh1 = *(const bf16x8*)(wbp + 512);
  bf16x8 Bh2 = *(const bf16x8*)(wbp + 1024);
  bf16x8 Bh3 = *(const bf16x8*)(wbp + 1536);
  bf16x8 Bl0 = *(const bf16x8*)(wbp + 2048);
  bf16x8 Bl1 = *(const bf16x8*)(wbp + 2560);
  bf16x8 Bl2 = *(const bf16x8*)(wbp + 3072);
  bf16x8 Bl3 = *(const bf16x8*)(wbp + 3584);
  const u16* row1 = h2t + (((long)b * 128 + (oh + 1)) << 7) * 32 + q * 8;
  const u16* row2 = row1 + 4096;
  float bv = (n < 3) ? bias[n] : 0.f;
  float lsum = 0.f;
  #pragma unroll
  for (int ti = 0; ti < 2; ++ti) {
    int tt = wv + ti * 4;
    int c1 = tt * 16 + n + 1;
    int c2 = c1 + 1;
    bf16x8 a11 = {}, a12 = {}, a21 = {}, a22 = {};
    if (c1 < 128) { a11 = *(const bf16x8*)(row1 + (c1 << 5));
                    a21 = *(const bf16x8*)(row2 + (c1 << 5)); }
    if (c2 < 128) { a12 = *(const bf16x8*)(row1 + (c2 << 5));
                    a22 = *(const bf16x8*)(row2 + (c2 << 5)); }
    f32x4 acc = {0.f, 0.f, 0.f, 0.f};
    acc = __builtin_amdgcn_mfma_f32_16x16x32_bf16(a11, Bh3, acc, 0, 0, 0);
    acc = __builtin_amdgcn_mfma_f32_16x16x32_bf16(a12, Bh2, acc, 0, 0, 0);
    acc = __builtin_amdgcn_mfma_f32_16x16x32_bf16(a21, Bh1, acc, 0, 0, 0);
    acc = __builtin_amdgcn_mfma_f32_16x16x32_bf16(a22, Bh0, acc, 0, 0, 0);
    acc = __builtin_amdgcn_mfma_f32_16x16x32_bf16(a11, Bl3, acc, 0, 0, 0);
    acc = __builtin_amdgcn_mfma_f32_16x16x32_bf16(a12, Bl2, acc, 0, 0, 0);
    acc = __builtin_amdgcn_mfma_f32_16x16x32_bf16(a21, Bl1, acc, 0, 0, 0);
    acc = __builtin_amdgcn_mfma_f32_16x16x32_bf16(a22, Bl0, acc, 0, 0, 0);
    if (n < 3) {
      int ow0 = tt * 16 + q * 4;
      int o = b * 46875 + n * 15625 + oh * 125 + ow0;
      if (ow0 + 3 < 125) {
        float4 v = make_float4(acc[0] + bv, acc[1] + bv, acc[2] + bv, acc[3] + bv);
        float4 xv = *(const float4*)(x + o);
        *(float4*)(xr + o) = v;
        float d0 = v.x - xv.x, d1 = v.y - xv.y, d2 = v.z - xv.z, d3 = v.w - xv.w;
        lsum += d0 * d0 + d1 * d1 + d2 * d2 + d3 * d3;
      } else {
        #pragma unroll
        for (int r = 0; r < 4; ++r) {
          if (ow0 + r < 125) {
            float v = acc[r] + bv;
            xr[o + r] = v;
            float d = v - x[o + r];
            lsum = fmaf(d, d, lsum);
          }
        }
      }
    }
  }
  __shared__ float red[256];
  red[t] = lsum; __syncthreads();
  #pragma unroll
  for (int s = 128; s > 0; s >>= 1) {
    if (t < s) red[t] += red[t + s];
    __syncthreads();
  }
  if (t == 0) psum[blockIdx.x] = red[0];
}

// ---------------- finalize: reduce 8000 partials + vq loss ----------------
__global__ __launch_bounds__(256) void k_fin(
    const float* __restrict__ acc, const float* __restrict__ psum,
    float* __restrict__ out) {
  int t = threadIdx.x;
  float s = 0.f;
  for (int i = t; i < 8000; i += 256) s += psum[i];
  __shared__ float red[256];
  red[t] = s; __syncthreads();
  #pragma unroll
  for (int k = 128; k > 0; k >>= 1) {
    if (t < k) red[t] += red[t + k];
    __syncthreads();
  }
  if (t == 0) {
    float eq  = 1.25f * acc[0] / 4194304.0f;
    float rec = red[0];
    out[0] = eq + rec;
    out[1] = eq;
    out[2] = rec;
  }
}

extern "C" void kernel_launch(void* const* d_in, const int* in_sizes, int n_in,
                              void* d_out, int out_size, void* d_ws, size_t ws_size,
                              hipStream_t stream) {
  (void)in_sizes; (void)n_in; (void)out_size; (void)ws_size;
  const float* x   = (const float*)d_in[0];
  const float* ew1 = (const float*)d_in[1];
  const float* eb1 = (const float*)d_in[2];
  const float* ew2 = (const float*)d_in[3];
  const float* eb2 = (const float*)d_in[4];
  const float* ew3 = (const float*)d_in[5];
  const float* eb3 = (const float*)d_in[6];
  const float* cb  = (const float*)d_in[7];
  const float* dw1 = (const float*)d_in[8];
  const float* db1 = (const float*)d_in[9];
  const float* dw2 = (const float*)d_in[10];
  const float* db2 = (const float*)d_in[11];
  const float* dw3 = (const float*)d_in[12];
  const float* db3 = (const float*)d_in[13];
  float* out = (float*)d_out;
  char*  ws  = (char*)d_ws;

  float*  acc  = (float*)(ws + 0);
  float*  c2   = (float*)(ws + 256);
  float*  wc1p = (float*)(ws + 4096);
  float*  wc3p = (float*)(ws + 8192);
  u16*    w3f  = (u16*)  (ws + 24576);
  u16*    w2f  = (u16*)  (ws + 36864);
  u16*    wt1g = (u16*)  (ws + 73728);     // 73728 B
  u16*    wt2g = (u16*)  (ws + 147456);    // 36864 B
  float*  psum = (float*)(ws + 184320);
  u16*    cbf  = (u16*)  (ws + 262144);    // ends 393216
  u16*    z1t  = (u16*)  (ws + 1048576);   // 16515072 B
  float*  z2   = (float*)(ws + 18874368);  // 16777216 B
  float*  z3   = (float*)(ws + 35651584);  // 16777216 B
  int*    idxb = (int*)  (ws + 52428800);  //   262144 B
  u16*    et   = (u16*)  (ws + 54525952);  //  8388608 B
  u16*    h1t  = (u16*)  (ws + 1048576);   // 33030144 B (over dead z1t/z2)
  u16*    h2t  = (u16*)  (ws + 67108864);  // 67108864 B -> ends 134217728
  u16*    z3h  = (u16*)  (ws + 134217728); //  8388608 B
  u16*    z3l  = (u16*)  (ws + 142606336); //  8388608 B -> ends 150994944
  float*  xp   = (float*)(ws + 150994944); // 12681216 B -> ends 163676160

  hipMemsetAsync(acc, 0, 64, stream);
  k_prep  <<<582,  256, 0, stream>>>(ew1, ew2, ew3, dw1, dw2, dw3, cb,
                                     wc1p, wc3p, w3f, c2, w2f, wt1g, wt2g, cbf);
  k_pad   <<<3096, 256, 0, stream>>>(x, xp);
  k_conv1 <<<1024, 256, 0, stream>>>(xp, wc1p, eb1, z1t);
  k_conv2 <<<2048, 256, 0, stream>>>(z1t, w2f, eb2, z2);
  k_conv3 <<<512,  256, 0, stream>>>(z2, wc3p, eb3, z3, z3h, z3l);
  k_vqp   <<<256,  256, 0, stream>>>(z3h, z3l, cbf, c2, idxb);
  k_vqf   <<<256,  256, 0, stream>>>(z3, cb, idxb, et, acc);
  k_convT1<<<1024, 256, 0, stream>>>(et, wt1g, db1, h1t);
  k_convT2<<<2048, 256, 0, stream>>>(h1t, wt2g, db2, h2t);
  k_convT3<<<8000, 256, 0, stream>>>(h2t, w3f, db3, x, out + 3, psum);
  k_fin   <<<1,    256, 0, stream>>>(acc, psum, out);
}

// Round 13
// 307.022 us; speedup vs baseline: 1.0597x; 1.0597x over previous
//
#include <hip/hip_runtime.h>

#define DEV __device__ __forceinline__
typedef unsigned short u16;
typedef __bf16 bf16x8 __attribute__((ext_vector_type(8)));
typedef float f32x4 __attribute__((ext_vector_type(4)));

DEV u16 f2bf(float f) {                      // RNE f32 -> bf16
  unsigned u = __float_as_uint(f);
  u += 0x7FFF + ((u >> 16) & 1);
  return (u16)(u >> 16);
}

// ---------------- geometry ----------------
// x    [64,3,125,125] fp32
// xp   [64,3,129,128] fp32 zero-padded
// z1t  [64,63,64,32]  bf16
// z2   [64,64,32,32]  fp32
// z3   [64,64,32,32]  fp32  + z3h/z3l [65536][64] bf16
// e_t  [64,32,32,64]  bf16  pixel-major
// h1t  [64,64,64,64]  bf16  pixel-major
// h2t  [64,128,128,32] bf16 pixel-major
// xr   [64,3,125,125] fp32

// ---------------- prep ----------------
__global__ __launch_bounds__(256) void k_prep(
    const float* __restrict__ ew1, const float* __restrict__ ew2,
    const float* __restrict__ ew3, const float* __restrict__ dw1,
    const float* __restrict__ dw2, const float* __restrict__ dw3,
    const float* __restrict__ cb,
    float* __restrict__ wc1p, float* __restrict__ wc3p,
    u16* __restrict__ w3f, float* __restrict__ c2,
    u16* __restrict__ w2f, u16* __restrict__ wt1f, u16* __restrict__ wt2f,
    u16* __restrict__ cbf) {
  int i = blockIdx.x * 256 + threadIdx.x;
  if (i < 864) {
    int cl = i & 7; int t = i >> 3; int tap = t % 9; t /= 9; int ci = t % 3; int cog = t / 3;
    wc1p[i] = ew1[((cog * 8 + cl) * 3 + ci) * 9 + tap];
  } else if (i < 4960) {
    int j = i - 864; int cl = j & 7; int t = j >> 3; int ci = t & 63; int cog = t >> 6;
    wc3p[j] = ew3[(cog * 8 + cl) * 64 + ci];
  } else if (i < 9056) {
    int j = i - 4960;                       // [hl][tp][lane][8]
    int jj = j & 7; int lane = (j >> 3) & 63; int tp = (j >> 9) & 3; int hl = j >> 11;
    int kh = tp >> 1, kw = tp & 1;
    int ci = ((lane >> 4) << 3) + jj; int co = lane & 15;
    float wv = (co < 3) ? dw3[((ci * 3 + co) * 2 + kh) * 2 + kw] : 0.f;
    u16 hi = f2bf(wv);
    if (hl == 0) w3f[j] = hi;
    else         w3f[j] = f2bf(wv - __uint_as_float((unsigned)hi << 16));
  } else if (i < 9568) {
    int k = i - 9056;
    const float4* c4 = (const float4*)(cb + (k << 6));
    float s = 0.f;
    #pragma unroll
    for (int q = 0; q < 16; ++q) { float4 v = c4[q]; s += v.x*v.x + v.y*v.y + v.z*v.z + v.w*v.w; }
    c2[k] = s;
  } else if (i < 28000) {
    int j = i - 9568;                       // [kt][nf][lane][8]
    int jj = j & 7; int lane = (j >> 3) & 63; int nf = (j >> 9) & 3; int kt = j >> 11;
    int kh = kt / 3, kw = kt % 3;
    int ci = ((lane >> 4) << 3) + jj; int co = (nf << 4) + (lane & 15);
    w2f[j] = f2bf(ew2[((co * 32 + ci) * 3 + kh) * 3 + kw]);
  } else if (i < 64864) {
    int j = i - 28000;                      // [kt][s][nf][lane][8]
    int jj = j & 7; int lane = (j >> 3) & 63; int nf = (j >> 9) & 3; int s = (j >> 11) & 1; int kt = j >> 12;
    int kh = kt / 3, kw = kt % 3;
    int ci = (s << 5) + ((lane >> 4) << 3) + jj; int co = (nf << 4) + (lane & 15);
    wt1f[j] = f2bf(dw1[((ci * 64 + co) * 3 + kh) * 3 + kw]);
  } else if (i < 83296) {
    int j = i - 64864;                      // [kt][s][nf][lane][8]
    int jj = j & 7; int lane = (j >> 3) & 63; int nf = (j >> 9) & 1; int s = (j >> 10) & 1; int kt = j >> 11;
    int kh = kt / 3, kw = kt % 3;
    int ci = (s << 5) + ((lane >> 4) << 3) + jj; int co = (nf << 4) + (lane & 15);
    wt2f[j] = f2bf(dw2[((ci * 32 + co) * 3 + kh) * 3 + kw]);
  } else if (i < 148832) {
    int j = i - 83296;                      // [hl][ks][nt][lane][8]
    int jj = j & 7; int lane = (j >> 3) & 63; int nt = (j >> 9) & 31; int ks = (j >> 14) & 1; int hl = j >> 15;
    int ci = (ks << 5) + ((lane >> 4) << 3) + jj;
    int code = (nt << 4) + (lane & 15);
    float v = cb[(code << 6) + ci];
    u16 hi = f2bf(v);
    cbf[j] = hl ? f2bf(v - __uint_as_float((unsigned)hi << 16)) : hi;
  }
}

// ---------------- pad: x -> xp [64*3][129][128], zero borders ----------------
__global__ __launch_bounds__(256) void k_pad(
    const float* __restrict__ x, float* __restrict__ xp) {
  int idx = blockIdx.x * 256 + threadIdx.x;
  int c4 = idx & 31;
  int r  = (idx >> 5) % 129;
  int cbp = (idx >> 5) / 129;
  int ih = r - 1;
  float4 v = make_float4(0.f, 0.f, 0.f, 0.f);
  if ((unsigned)ih < 125u) {
    const float* rp = x + (cbp * 125 + ih) * 125;
    int iw0 = c4 * 4 - 1;
    if (iw0 >= 0)        v.x = rp[iw0];
    if (iw0 + 1 < 125)   v.y = rp[iw0 + 1];
    if (iw0 + 2 < 125)   v.z = rp[iw0 + 2];
    if (iw0 + 3 < 125)   v.w = rp[iw0 + 3];
  }
  *(float4*)(xp + (cbp * 129 + r) * 128 + c4 * 4) = v;
}

// ---------------- conv1: padded input, all-co blocks, LDS wide stores ----------------
__global__ __launch_bounds__(256) void k_conv1(
    const float* __restrict__ xp, const float* __restrict__ wp,
    const float* __restrict__ bias, u16* __restrict__ z1t) {
  __shared__ u16 st[256 * 34];
  int t = threadIdx.x;
  int slab = blockIdx.x & 15, b = blockIdx.x >> 4;   // grid 1024
  int tx = t & 15, ty = (t >> 4) & 3, cg = t >> 6;
  int oh = slab * 4 + ty;
  int co0 = cg * 8;
  const float* wcg = wp + cg * 216;
  float acc[8][4];
  #pragma unroll
  for (int c = 0; c < 8; ++c) {
    float bv = bias[co0 + c];
    #pragma unroll
    for (int s = 0; s < 4; ++s) acc[c][s] = bv;
  }
  #pragma unroll
  for (int ci = 0; ci < 3; ++ci) {
    #pragma unroll
    for (int kh = 0; kh < 3; ++kh) {
      const float* rp = xp + ((b * 3 + ci) * 129 + (2 * oh + kh)) * 128 + 8 * tx;
      float4 qa = *(const float4*)rp;
      float4 qb = *(const float4*)(rp + 4);
      float v8 = rp[8];
      float v[9] = {qa.x, qa.y, qa.z, qa.w, qb.x, qb.y, qb.z, qb.w, v8};
      #pragma unroll
      for (int kw = 0; kw < 3; ++kw) {
        const float* wq = wcg + (ci * 9 + kh * 3 + kw) * 8;
        float4 wa = *(const float4*)wq;
        float4 wb = *(const float4*)(wq + 4);
        float w8[8] = {wa.x, wa.y, wa.z, wa.w, wb.x, wb.y, wb.z, wb.w};
        #pragma unroll
        for (int s = 0; s < 4; ++s) {
          float in = v[2 * s + kw];
          #pragma unroll
          for (int c = 0; c < 8; ++c) acc[c][s] = fmaf(in, w8[c], acc[c][s]);
        }
      }
    }
  }
  #pragma unroll
  for (int s = 0; s < 4; ++s) {
    bool wok = (tx * 4 + s) < 63;
    unsigned p0 = 0, p1 = 0, p2 = 0, p3 = 0;
    if (wok) {
      p0 = f2bf(fmaxf(acc[0][s], 0.f)) | ((unsigned)f2bf(fmaxf(acc[1][s], 0.f)) << 16);
      p1 = f2bf(fmaxf(acc[2][s], 0.f)) | ((unsigned)f2bf(fmaxf(acc[3][s], 0.f)) << 16);
      p2 = f2bf(fmaxf(acc[4][s], 0.f)) | ((unsigned)f2bf(fmaxf(acc[5][s], 0.f)) << 16);
      p3 = f2bf(fmaxf(acc[6][s], 0.f)) | ((unsigned)f2bf(fmaxf(acc[7][s], 0.f)) << 16);
    }
    int lpix = tx * 16 + ty * 4 + s;
    *(uint4*)&st[lpix * 34 + co0] = make_uint4(p0, p1, p2, p3);
  }
  __syncthreads();
  {
    int p = t;
    int ow = (p >> 4) * 4 + (p & 3);
    int ohl = (p >> 2) & 3;
    int oho = slab * 4 + ohl;
    if (oho < 63) {
      const u16* lp = &st[p * 34];
      uint4 a0 = *(const uint4*)(lp);
      uint4 a1 = *(const uint4*)(lp + 8);
      uint4 a2 = *(const uint4*)(lp + 16);
      uint4 a3 = *(const uint4*)(lp + 24);
      uint4* gp = (uint4*)(z1t + ((b * 63 + oho) * 64 + ow) * 32);
      gp[0] = a0; gp[1] = a1; gp[2] = a2; gp[3] = a3;
    }
  }
}

// ---------------- conv2: MFMA, block=(b,oh), waves=(xt2, ch2) ----------------
__global__ __launch_bounds__(256) void k_conv2(
    const u16* __restrict__ z1t, const u16* __restrict__ wf,
    const float* __restrict__ bias, float* __restrict__ z2) {
  int t = threadIdx.x;
  int lane = t & 63, wv = t >> 6;
  int n = lane & 15, q = lane >> 4;
  int oh = blockIdx.x & 31, b = blockIdx.x >> 5;   // grid 2048
  int xt = wv & 1, ch = wv >> 1;
  int xA = xt * 16 + n;
  f32x4 acc[2] = {{0,0,0,0},{0,0,0,0}};
  #pragma unroll
  for (int kh = 0; kh < 3; ++kh) {
    int ih = 2 * oh - 1 + kh;
    bool yok = (unsigned)ih < 63u;
    #pragma unroll
    for (int kw = 0; kw < 3; ++kw) {
      int iw = 2 * xA - 1 + kw;
      bool ok = yok && (iw >= 0);
      bf16x8 a = {};
      if (ok) a = *(const bf16x8*)(z1t + ((b * 63 + ih) * 64 + iw) * 32 + q * 8);
      int kt = kh * 3 + kw;
      const u16* wb = wf + ((kt << 2) + (ch << 1)) * 512 + lane * 8;
      bf16x8 b0 = *(const bf16x8*)wb;
      bf16x8 b1 = *(const bf16x8*)(wb + 512);
      acc[0] = __builtin_amdgcn_mfma_f32_16x16x32_bf16(a, b0, acc[0], 0, 0, 0);
      acc[1] = __builtin_amdgcn_mfma_f32_16x16x32_bf16(a, b1, acc[1], 0, 0, 0);
    }
  }
  #pragma unroll
  for (int j = 0; j < 2; ++j) {
    int co = ((ch << 1) + j) * 16 + n;
    float bv = bias[co];
    float4 rv = make_float4(fmaxf(acc[j][0] + bv, 0.f), fmaxf(acc[j][1] + bv, 0.f),
                            fmaxf(acc[j][2] + bv, 0.f), fmaxf(acc[j][3] + bv, 0.f));
    *(float4*)(z2 + ((b * 64 + co) * 32 + oh) * 32 + xt * 16 + q * 4) = rv;
  }
}

// ---------------- conv3 (1x1): fp32, + LDS transpose to pixel-major hi/lo ----------------
__global__ __launch_bounds__(256) void k_conv3(
    const float* __restrict__ in, const float* __restrict__ wp,
    const float* __restrict__ bias, float* __restrict__ z3,
    u16* __restrict__ z3h, u16* __restrict__ z3l) {
  __shared__ u16 lh[128 * 72];
  __shared__ u16 ll[128 * 72];
  int t = threadIdx.x;
  int pxg = blockIdx.x & 7; int b = blockIdx.x >> 3;   // grid 512
  int pxi = t & 31, cog = t >> 5;
  int px0 = pxg * 128 + pxi * 4;
  const float* wcg = wp + cog * 512;
  int co0 = cog * 8;
  float acc[8][4];
  #pragma unroll
  for (int c = 0; c < 8; ++c) {
    float bv = bias[co0 + c];
    #pragma unroll
    for (int s = 0; s < 4; ++s) acc[c][s] = bv;
  }
  const float* ip = in + (b << 16) + px0;
  for (int ci = 0; ci < 64; ++ci) {
    float4 v = *(const float4*)(ip + (ci << 10));
    float4 wa = *(const float4*)(wcg + ci * 8);
    float4 wb = *(const float4*)(wcg + ci * 8 + 4);
    float w8[8] = {wa.x, wa.y, wa.z, wa.w, wb.x, wb.y, wb.z, wb.w};
    #pragma unroll
    for (int c = 0; c < 8; ++c) {
      acc[c][0] = fmaf(v.x, w8[c], acc[c][0]);
      acc[c][1] = fmaf(v.y, w8[c], acc[c][1]);
      acc[c][2] = fmaf(v.z, w8[c], acc[c][2]);
      acc[c][3] = fmaf(v.w, w8[c], acc[c][3]);
    }
  }
  float* op = z3 + ((b << 6) + co0) * 1024 + px0;
  #pragma unroll
  for (int c = 0; c < 8; ++c)
    *(float4*)(op + (c << 10)) = make_float4(acc[c][0], acc[c][1], acc[c][2], acc[c][3]);
  #pragma unroll
  for (int s = 0; s < 4; ++s) {
    unsigned h[4], l[4];
    #pragma unroll
    for (int g = 0; g < 4; ++g) {
      float v0 = acc[2 * g][s], v1 = acc[2 * g + 1][s];
      u16 h0 = f2bf(v0), h1 = f2bf(v1);
      u16 l0 = f2bf(v0 - __uint_as_float((unsigned)h0 << 16));
      u16 l1 = f2bf(v1 - __uint_as_float((unsigned)h1 << 16));
      h[g] = h0 | ((unsigned)h1 << 16);
      l[g] = l0 | ((unsigned)l1 << 16);
    }
    int la = (pxi * 4 + s) * 72 + co0;
    *(uint4*)&lh[la] = make_uint4(h[0], h[1], h[2], h[3]);
    *(uint4*)&ll[la] = make_uint4(l[0], l[1], l[2], l[3]);
  }
  __syncthreads();
  {
    int p = t >> 1, half = t & 1;
    int la = p * 72 + half * 32;
    uint4 h0 = *(uint4*)&lh[la],      h1 = *(uint4*)&lh[la + 8];
    uint4 h2 = *(uint4*)&lh[la + 16], h3 = *(uint4*)&lh[la + 24];
    uint4 l0 = *(uint4*)&ll[la],      l1 = *(uint4*)&ll[la + 8];
    uint4 l2 = *(uint4*)&ll[la + 16], l3 = *(uint4*)&ll[la + 24];
    long gp = ((long)b * 1024 + pxg * 128 + p) * 64 + half * 32;
    uint4* oh = (uint4*)(z3h + gp);
    uint4* ol = (uint4*)(z3l + gp);
    oh[0] = h0; oh[1] = h1; oh[2] = h2; oh[3] = h3;
    ol[0] = l0; ol[1] = l1; ol[2] = l2; ol[3] = l3;
  }
}

// ---------------- VQ argmin: MFMA hi/lo, 64 px/wave x 512 codes ----------------
__global__ __launch_bounds__(256) void k_vqp(
    const u16* __restrict__ z3h, const u16* __restrict__ z3l,
    const u16* __restrict__ cbf, const float* __restrict__ c2v,
    int* __restrict__ idxb) {
  int t = threadIdx.x;
  int lane = t & 63, wv = t >> 6;
  int n = lane & 15, q = lane >> 4;
  int p0 = (blockIdx.x * 4 + wv) * 64;               // grid 256
  bf16x8 Ah[4][2], Al[4][2];
  #pragma unroll
  for (int mt = 0; mt < 4; ++mt) {
    const u16* ap = z3h + (p0 + mt * 16 + n) * 64 + q * 8;
    const u16* al = z3l + (p0 + mt * 16 + n) * 64 + q * 8;
    Ah[mt][0] = *(const bf16x8*)ap;  Ah[mt][1] = *(const bf16x8*)(ap + 32);
    Al[mt][0] = *(const bf16x8*)al;  Al[mt][1] = *(const bf16x8*)(al + 32);
  }
  float bs[4][4]; int bix[4][4];
  #pragma unroll
  for (int mt = 0; mt < 4; ++mt)
    #pragma unroll
    for (int r = 0; r < 4; ++r) { bs[mt][r] = 3.4e38f; bix[mt][r] = 0; }
  for (int nt = 0; nt < 32; ++nt) {
    const u16* bp = cbf + lane * 8;
    bf16x8 Bh0 = *(const bf16x8*)(bp + (nt << 9));
    bf16x8 Bh1 = *(const bf16x8*)(bp + ((32 + nt) << 9));
    bf16x8 Bl0 = *(const bf16x8*)(bp + ((64 + nt) << 9));
    bf16x8 Bl1 = *(const bf16x8*)(bp + ((96 + nt) << 9));
    float c2 = c2v[(nt << 4) + n];
    #pragma unroll
    for (int mt = 0; mt < 4; ++mt) {
      f32x4 acc = {0.f, 0.f, 0.f, 0.f};
      acc = __builtin_amdgcn_mfma_f32_16x16x32_bf16(Ah[mt][0], Bh0, acc, 0, 0, 0);
      acc = __builtin_amdgcn_mfma_f32_16x16x32_bf16(Ah[mt][1], Bh1, acc, 0, 0, 0);
      acc = __builtin_amdgcn_mfma_f32_16x16x32_bf16(Al[mt][0], Bh0, acc, 0, 0, 0);
      acc = __builtin_amdgcn_mfma_f32_16x16x32_bf16(Al[mt][1], Bh1, acc, 0, 0, 0);
      acc = __builtin_amdgcn_mfma_f32_16x16x32_bf16(Ah[mt][0], Bl0, acc, 0, 0, 0);
      acc = __builtin_amdgcn_mfma_f32_16x16x32_bf16(Ah[mt][1], Bl1, acc, 0, 0, 0);
      int idx = (nt << 4) + n;
      #pragma unroll
      for (int r = 0; r < 4; ++r) {
        float sc = fmaf(-2.f, acc[r], c2);
        if (sc < bs[mt][r]) { bs[mt][r] = sc; bix[mt][r] = idx; }
      }
    }
  }
  #pragma unroll
  for (int off = 8; off > 0; off >>= 1) {
    #pragma unroll
    for (int mt = 0; mt < 4; ++mt)
      #pragma unroll
      for (int r = 0; r < 4; ++r) {
        float os = __shfl_xor(bs[mt][r], off, 16);
        int oi = __shfl_xor(bix[mt][r], off, 16);
        if (os < bs[mt][r] || (os == bs[mt][r] && oi < bix[mt][r])) {
          bs[mt][r] = os; bix[mt][r] = oi;
        }
      }
  }
  if (n == 0) {
    #pragma unroll
    for (int mt = 0; mt < 4; ++mt)
      #pragma unroll
      for (int r = 0; r < 4; ++r)
        idxb[p0 + mt * 16 + q * 4 + r] = bix[mt][r];
  }
}

// ---------------- VQ finalize: gather, write e_t bf16, loss ----------------
__global__ __launch_bounds__(256) void k_vqf(
    const float* __restrict__ z3, const float* __restrict__ cb,
    const int* __restrict__ idxb, u16* __restrict__ et,
    float* __restrict__ acc) {
  int n = blockIdx.x * 256 + threadIdx.x;  // 65536
  int bi = idxb[n];
  int b = n >> 10, hw = n & 1023;
  const float* zp = z3 + (b << 16) + hw;
  uint2* ep = (uint2*)(et + (n << 6));
  const float4* cq = (const float4*)(cb + (bi << 6));
  float lsum = 0.f;
  #pragma unroll
  for (int i = 0; i < 16; ++i) {
    float4 c = cq[i];
    float zv, df;
    zv = zp[(4*i+0) << 10]; df = c.x - zv; lsum = fmaf(df, df, lsum);
    zv = zp[(4*i+1) << 10]; df = c.y - zv; lsum = fmaf(df, df, lsum);
    zv = zp[(4*i+2) << 10]; df = c.z - zv; lsum = fmaf(df, df, lsum);
    zv = zp[(4*i+3) << 10]; df = c.w - zv; lsum = fmaf(df, df, lsum);
    ep[i] = make_uint2(f2bf(c.x) | ((unsigned)f2bf(c.y) << 16),
                       f2bf(c.z) | ((unsigned)f2bf(c.w) << 16));
  }
  __shared__ float red[256];
  red[threadIdx.x] = lsum; __syncthreads();
  #pragma unroll
  for (int s = 128; s > 0; s >>= 1) {
    if (threadIdx.x < s) red[threadIdx.x] += red[threadIdx.x + s];
    __syncthreads();
  }
  if (threadIdx.x == 0) atomicAdd(acc + 0, red[0]);
}

// ---------------- convT1: parity-pair, cog-split blocks, LDS weights + stores ----------------
// block = (b, yg, cog): 2 y-pairs, half the co. waves = (yw2, xt2). grid 2048.
__global__ __launch_bounds__(256) void k_convT1(
    const u16* __restrict__ et, const u16* __restrict__ wf,
    const float* __restrict__ bias, u16* __restrict__ h1t) {
  __shared__ u16 wl[36 * 512];      // 36864 B: [kt9][j2][ks2][lane64*8]
  __shared__ u16 st[4][64 * 34];    // 17408 B
  int t = threadIdx.x;
  int lane = t & 63, wv = t >> 6;
  int yw = wv & 1, xt = wv >> 1;
  int cog = blockIdx.x & 1;
  int yg = (blockIdx.x >> 1) & 15;
  int b = blockIdx.x >> 5;           // grid 2048
  // stage cog-specific weights
  {
    const uint4* gw = (const uint4*)wf;
    uint4* lw = (uint4*)wl;
    #pragma unroll
    for (int k = 0; k < 9; ++k) {
      int i = t + 256 * k;           // 0..2303
      int slot = i >> 6, within = i & 63;
      int kt = slot >> 2, j = (slot >> 1) & 1, ks = slot & 1;
      int goff = (kt << 12) + (((ks << 2) + (cog << 1) + j) << 9);  // u16 units
      lw[i] = gw[(goff >> 3) + within];
    }
  }
  int y = yg * 2 + yw;
  int n = lane & 15, q = lane >> 4;
  int m = xt * 16 + n;
  const u16* base0 = et + (((b * 32 + y) * 32) << 6) + q * 8;
  bf16x8 P00a, P00b, P01a = {}, P01b = {}, P10a = {}, P10b = {}, P11a = {}, P11b = {};
  { const u16* p = base0 + (m << 6); P00a = *(const bf16x8*)p; P00b = *(const bf16x8*)(p + 32); }
  if (m + 1 < 32) { const u16* p = base0 + ((m + 1) << 6); P01a = *(const bf16x8*)p; P01b = *(const bf16x8*)(p + 32); }
  if (y + 1 < 32) {
    const u16* base1 = base0 + (32 << 6);
    { const u16* p = base1 + (m << 6); P10a = *(const bf16x8*)p; P10b = *(const bf16x8*)(p + 32); }
    if (m + 1 < 32) { const u16* p = base1 + ((m + 1) << 6); P11a = *(const bf16x8*)p; P11b = *(const bf16x8*)(p + 32); }
  }
  __syncthreads();
  f32x4 accE[2][2] = {};  // [j][pwi]
  f32x4 accO[2][2] = {};
  #pragma unroll
  for (int kw = 0; kw < 3; ++kw) {
    int pwi = (kw == 1) ? 0 : 1;
    bf16x8 A0a = (kw == 0) ? P01a : P00a;   // row y
    bf16x8 A0b = (kw == 0) ? P01b : P00b;
    bf16x8 A1a = (kw == 0) ? P11a : P10a;   // row y+1
    bf16x8 A1b = (kw == 0) ? P11b : P10b;
    #pragma unroll
    for (int j = 0; j < 2; ++j) {
      const u16* wE  = wl + ((((3 + kw) << 2) + (j << 1)) << 9) + lane * 8;
      const u16* wO0 = wl + (((kw << 2) + (j << 1)) << 9) + lane * 8;
      const u16* wO2 = wl + ((((6 + kw) << 2) + (j << 1)) << 9) + lane * 8;
      bf16x8 bE0 = *(const bf16x8*)wE;
      bf16x8 bE1 = *(const bf16x8*)(wE + 512);
      accE[j][pwi] = __builtin_amdgcn_mfma_f32_16x16x32_bf16(A0a, bE0, accE[j][pwi], 0, 0, 0);
      accE[j][pwi] = __builtin_amdgcn_mfma_f32_16x16x32_bf16(A0b, bE1, accE[j][pwi], 0, 0, 0);
      bf16x8 bO00 = *(const bf16x8*)wO0;
      bf16x8 bO01 = *(const bf16x8*)(wO0 + 512);
      accO[j][pwi] = __builtin_amdgcn_mfma_f32_16x16x32_bf16(A1a, bO00, accO[j][pwi], 0, 0, 0);
      accO[j][pwi] = __builtin_amdgcn_mfma_f32_16x16x32_bf16(A1b, bO01, accO[j][pwi], 0, 0, 0);
      bf16x8 bO20 = *(const bf16x8*)wO2;
      bf16x8 bO21 = *(const bf16x8*)(wO2 + 512);
      accO[j][pwi] = __builtin_amdgcn_mfma_f32_16x16x32_bf16(A0a, bO20, accO[j][pwi], 0, 0, 0);
      accO[j][pwi] = __builtin_amdgcn_mfma_f32_16x16x32_bf16(A0b, bO21, accO[j][pwi], 0, 0, 0);
    }
  }
  #pragma unroll
  for (int j = 0; j < 2; ++j) {
    int col = j * 16 + n;            // local co within cog half
    float bv = bias[cog * 32 + col];
    #pragma unroll
    for (int pw = 0; pw < 2; ++pw)
      #pragma unroll
      for (int r = 0; r < 4; ++r) {
        int ow = 2 * (xt * 16 + q * 4 + r) + pw;
        st[yw * 2 + 0][ow * 34 + col] = f2bf(fmaxf(accE[j][pw][r] + bv, 0.f));
        st[yw * 2 + 1][ow * 34 + col] = f2bf(fmaxf(accO[j][pw][r] + bv, 0.f));
      }
  }
  __syncthreads();
  {
    int row = t >> 6, ow = t & 63;   // 4 rows x 64 ow
    const u16* lp = &st[row][ow * 34];
    uint4* gp = (uint4*)(h1t + (((b * 64 + yg * 4 + row) * 64 + ow) << 6) + cog * 32);
    gp[0] = *(const uint4*)(lp);
    gp[1] = *(const uint4*)(lp + 8);
    gp[2] = *(const uint4*)(lp + 16);
    gp[3] = *(const uint4*)(lp + 24);
  }
}

// ---------------- convT2: parity-pair blocks, LDS weights + stores ----------------
// block = (b, y): outputs oh=2y, 2y+1. waves = xt4. grid 4096.
__global__ __launch_bounds__(256) void k_convT2(
    const u16* __restrict__ h1t, const u16* __restrict__ wf,
    const float* __restrict__ bias, u16* __restrict__ h2t) {
  __shared__ u16 wl[18432];         // 36864 B full table
  __shared__ u16 st[2][128 * 34];   // 17408 B
  int t = threadIdx.x;
  int lane = t & 63, xt = t >> 6;
  int n = lane & 15, q = lane >> 4;
  int y = blockIdx.x & 63, b = blockIdx.x >> 6;
  // stage weights
  {
    const uint4* gw = (const uint4*)wf;
    uint4* lw = (uint4*)wl;
    #pragma unroll
    for (int k = 0; k < 9; ++k) lw[t + 256 * k] = gw[t + 256 * k];
  }
  int m = xt * 16 + n;
  const u16* base0 = h1t + (((b * 64 + y) * 64) << 6) + q * 8;
  bf16x8 P00a, P00b, P01a = {}, P01b = {}, P10a = {}, P10b = {}, P11a = {}, P11b = {};
  { const u16* p = base0 + (m << 6); P00a = *(const bf16x8*)p; P00b = *(const bf16x8*)(p + 32); }
  if (m + 1 < 64) { const u16* p = base0 + ((m + 1) << 6); P01a = *(const bf16x8*)p; P01b = *(const bf16x8*)(p + 32); }
  if (y + 1 < 64) {
    const u16* base1 = base0 + (64 << 6);
    { const u16* p = base1 + (m << 6); P10a = *(const bf16x8*)p; P10b = *(const bf16x8*)(p + 32); }
    if (m + 1 < 64) { const u16* p = base1 + ((m + 1) << 6); P11a = *(const bf16x8*)p; P11b = *(const bf16x8*)(p + 32); }
  }
  __syncthreads();
  f32x4 accE[2][2] = {};  // [nf][pwi]
  f32x4 accO[2][2] = {};
  #pragma unroll
  for (int kw = 0; kw < 3; ++kw) {
    int pwi = (kw == 1) ? 0 : 1;
    bf16x8 A0a = (kw == 0) ? P01a : P00a;
    bf16x8 A0b = (kw == 0) ? P01b : P00b;
    bf16x8 A1a = (kw == 0) ? P11a : P10a;
    bf16x8 A1b = (kw == 0) ? P11b : P10b;
    const u16* wbE = wl + ((3 + kw) << 11) + lane * 8;
    const u16* wbO0 = wl + (kw << 11) + lane * 8;
    const u16* wbO2 = wl + ((6 + kw) << 11) + lane * 8;
    #pragma unroll
    for (int nf = 0; nf < 2; ++nf) {
      bf16x8 bE0 = *(const bf16x8*)(wbE + nf * 512);
      bf16x8 bE1 = *(const bf16x8*)(wbE + (2 + nf) * 512);
      accE[nf][pwi] = __builtin_amdgcn_mfma_f32_16x16x32_bf16(A0a, bE0, accE[nf][pwi], 0, 0, 0);
      accE[nf][pwi] = __builtin_amdgcn_mfma_f32_16x16x32_bf16(A0b, bE1, accE[nf][pwi], 0, 0, 0);
      bf16x8 bO00 = *(const bf16x8*)(wbO0 + nf * 512);
      bf16x8 bO01 = *(const bf16x8*)(wbO0 + (2 + nf) * 512);
      accO[nf][pwi] = __builtin_amdgcn_mfma_f32_16x16x32_bf16(A1a, bO00, accO[nf][pwi], 0, 0, 0);
      accO[nf][pwi] = __builtin_amdgcn_mfma_f32_16x16x32_bf16(A1b, bO01, accO[nf][pwi], 0, 0, 0);
      bf16x8 bO20 = *(const bf16x8*)(wbO2 + nf * 512);
      bf16x8 bO21 = *(const bf16x8*)(wbO2 + (2 + nf) * 512);
      accO[nf][pwi] = __builtin_amdgcn_mfma_f32_16x16x32_bf16(A0a, bO20, accO[nf][pwi], 0, 0, 0);
      accO[nf][pwi] = __builtin_amdgcn_mfma_f32_16x16x32_bf16(A0b, bO21, accO[nf][pwi], 0, 0, 0);
    }
  }
  #pragma unroll
  for (int nf = 0; nf < 2; ++nf) {
    int co = nf * 16 + n;
    float bv = bias[co];
    #pragma unroll
    for (int pw = 0; pw < 2; ++pw)
      #pragma unroll
      for (int r = 0; r < 4; ++r) {
        int ow = 2 * (xt * 16 + q * 4 + r) + pw;
        st[0][ow * 34 + co] = f2bf(fmaxf(accE[nf][pw][r] + bv, 0.f));
        st[1][ow * 34 + co] = f2bf(fmaxf(accO[nf][pw][r] + bv, 0.f));
      }
  }
  __syncthreads();
  int ow = t >> 1, sg = t & 1;
  #pragma unroll
  for (int l = 0; l < 2; ++l) {
    const u16* lp = &st[l][ow * 34 + sg * 16];
    unsigned w0 = *(const unsigned*)(lp + 0), w1 = *(const unsigned*)(lp + 2);
    unsigned w2 = *(const unsigned*)(lp + 4), w3 = *(const unsigned*)(lp + 6);
    unsigned w4 = *(const unsigned*)(lp + 8), w5 = *(const unsigned*)(lp + 10);
    unsigned w6 = *(const unsigned*)(lp + 12), w7 = *(const unsigned*)(lp + 14);
    uint4* gp = (uint4*)(h2t + ((((b * 128 + 2 * y + l) * 128) + ow) << 5) + sg * 16);
    gp[0] = make_uint4(w0, w1, w2, w3);
    gp[1] = make_uint4(w4, w5, w6, w7);
  }
}

// ---------------- convT3 + recon loss: MFMA, per-block partial sums ----------------
__global__ __launch_bounds__(256) void k_convT3(
    const u16* __restrict__ h2t, const u16* __restrict__ w3f,
    const float* __restrict__ bias, const float* __restrict__ x,
    float* __restrict__ xr, float* __restrict__ psum) {
  int t = threadIdx.x;
  int lane = t & 63, wv = t >> 6;
  int n = lane & 15, q = lane >> 4;
  int oh = blockIdx.x % 125, b = blockIdx.x / 125;   // grid 8000
  const u16* wbp = w3f + lane * 8;
  bf16x8 Bh0 = *(const bf16x8*)(wbp);
  bf16x8 Bh1 = *(const bf16x8*)(wbp + 512);
  bf16x8 Bh2 = *(const bf16x8*)(wbp + 1024);
  bf16x8 Bh3 = *(const bf16x8*)(wbp + 1536);
  bf16x8 Bl0 = *(const bf16x8*)(wbp + 2048);
  bf16x8 Bl1 = *(const bf16x8*)(wbp + 2560);
  bf16x8 Bl2 = *(const bf16x8*)(wbp + 3072);
  bf16x8 Bl3 = *(const bf16x8*)(wbp + 3584);
  const u16* row1 = h2t + (((long)b * 128 + (oh + 1)) << 7) * 32 + q * 8;
  const u16* row2 = row1 + 4096;
  float bv = (n < 3) ? bias[n] : 0.f;
  float lsum = 0.f;
  #pragma unroll
  for (int ti = 0; ti < 2; ++ti) {
    int tt = wv + ti * 4;
    int c1 = tt * 16 + n + 1;
    int c2 = c1 + 1;
    bf16x8 a11 = {}, a12 = {}, a21 = {}, a22 = {};
    if (c1 < 128) { a11 = *(const bf16x8*)(row1 + (c1 << 5));
                    a21 = *(const bf16x8*)(row2 + (c1 << 5)); }
    if (c2 < 128) { a12 = *(const bf16x8*)(row1 + (c2 << 5));
                    a22 = *(const bf16x8*)(row2 + (c2 << 5)); }
    f32x4 acc = {0.f, 0.f, 0.f, 0.f};
    acc = __builtin_amdgcn_mfma_f32_16x16x32_bf16(a11, Bh3, acc, 0, 0, 0);
    acc = __builtin_amdgcn_mfma_f32_16x16x32_bf16(a12, Bh2, acc, 0, 0, 0);
    acc = __builtin_amdgcn_mfma_f32_16x16x32_bf16(a21, Bh1, acc, 0, 0, 0);
    acc = __builtin_amdgcn_mfma_f32_16x16x32_bf16(a22, Bh0, acc, 0, 0, 0);
    acc = __builtin_amdgcn_mfma_f32_16x16x32_bf16(a11, Bl3, acc, 0, 0, 0);
    acc = __builtin_amdgcn_mfma_f32_16x16x32_bf16(a12, Bl2, acc, 0, 0, 0);
    acc = __builtin_amdgcn_mfma_f32_16x16x32_bf16(a21, Bl1, acc, 0, 0, 0);
    acc = __builtin_amdgcn_mfma_f32_16x16x32_bf16(a22, Bl0, acc, 0, 0, 0);
    if (n < 3) {
      int ow0 = tt * 16 + q * 4;
      int o = b * 46875 + n * 15625 + oh * 125 + ow0;
      if (ow0 + 3 < 125) {
        float4 v = make_float4(acc[0] + bv, acc[1] + bv, acc[2] + bv, acc[3] + bv);
        float4 xv = *(const float4*)(x + o);
        *(float4*)(xr + o) = v;
        float d0 = v.x - xv.x, d1 = v.y - xv.y, d2 = v.z - xv.z, d3 = v.w - xv.w;
        lsum += d0 * d0 + d1 * d1 + d2 * d2 + d3 * d3;
      } else {
        #pragma unroll
        for (int r = 0; r < 4; ++r) {
          if (ow0 + r < 125) {
            float v = acc[r] + bv;
            xr[o + r] = v;
            float d = v - x[o + r];
            lsum = fmaf(d, d, lsum);
          }
        }
      }
    }
  }
  __shared__ float red[256];
  red[t] = lsum; __syncthreads();
  #pragma unroll
  for (int s = 128; s > 0; s >>= 1) {
    if (t < s) red[t] += red[t + s];
    __syncthreads();
  }
  if (t == 0) psum[blockIdx.x] = red[0];
}

// ---------------- finalize: reduce 8000 partials + vq loss ----------------
__global__ __launch_bounds__(256) void k_fin(
    const float* __restrict__ acc, const float* __restrict__ psum,
    float* __restrict__ out) {
  int t = threadIdx.x;
  float s = 0.f;
  for (int i = t; i < 8000; i += 256) s += psum[i];
  __shared__ float red[256];
  red[t] = s; __syncthreads();
  #pragma unroll
  for (int k = 128; k > 0; k >>= 1) {
    if (t < k) red[t] += red[t + k];
    __syncthreads();
  }
  if (t == 0) {
    float eq  = 1.25f * acc[0] / 4194304.0f;
    float rec = red[0];
    out[0] = eq + rec;
    out[1] = eq;
    out[2] = rec;
  }
}

extern "C" void kernel_launch(void* const* d_in, const int* in_sizes, int n_in,
                              void* d_out, int out_size, void* d_ws, size_t ws_size,
                              hipStream_t stream) {
  (void)in_sizes; (void)n_in; (void)out_size; (void)ws_size;
  const float* x   = (const float*)d_in[0];
  const float* ew1 = (const float*)d_in[1];
  const float* eb1 = (const float*)d_in[2];
  const float* ew2 = (const float*)d_in[3];
  const float* eb2 = (const float*)d_in[4];
  const float* ew3 = (const float*)d_in[5];
  const float* eb3 = (const float*)d_in[6];
  const float* cb  = (const float*)d_in[7];
  const float* dw1 = (const float*)d_in[8];
  const float* db1 = (const float*)d_in[9];
  const float* dw2 = (const float*)d_in[10];
  const float* db2 = (const float*)d_in[11];
  const float* dw3 = (const float*)d_in[12];
  const float* db3 = (const float*)d_in[13];
  float* out = (float*)d_out;
  char*  ws  = (char*)d_ws;

  float*  acc  = (float*)(ws + 0);
  float*  c2   = (float*)(ws + 256);
  float*  wc1p = (float*)(ws + 4096);
  float*  wc3p = (float*)(ws + 8192);
  u16*    w3f  = (u16*)  (ws + 24576);
  u16*    w2f  = (u16*)  (ws + 36864);
  u16*    wt1f = (u16*)  (ws + 73728);     // 73728 B
  u16*    wt2f = (u16*)  (ws + 147456);    // 36864 B
  float*  psum = (float*)(ws + 184320);
  u16*    cbf  = (u16*)  (ws + 262144);    // ends 393216
  u16*    z1t  = (u16*)  (ws + 1048576);   // 16515072 B
  float*  z2   = (float*)(ws + 18874368);  // 16777216 B
  float*  z3   = (float*)(ws + 35651584);  // 16777216 B
  int*    idxb = (int*)  (ws + 52428800);  //   262144 B
  u16*    et   = (u16*)  (ws + 54525952);  //  8388608 B
  u16*    h1t  = (u16*)  (ws + 1048576);   // 33030144 B (over dead z1t/z2)
  u16*    h2t  = (u16*)  (ws + 67108864);  // 67108864 B -> ends 134217728
  u16*    z3h  = (u16*)  (ws + 134217728); //  8388608 B
  u16*    z3l  = (u16*)  (ws + 142606336); //  8388608 B -> ends 150994944
  float*  xp   = (float*)(ws + 150994944); // 12681216 B -> ends 163676160

  hipMemsetAsync(acc, 0, 64, stream);
  k_prep  <<<582,  256, 0, stream>>>(ew1, ew2, ew3, dw1, dw2, dw3, cb,
                                     wc1p, wc3p, w3f, c2, w2f, wt1f, wt2f, cbf);
  k_pad   <<<3096, 256, 0, stream>>>(x, xp);
  k_conv1 <<<1024, 256, 0, stream>>>(xp, wc1p, eb1, z1t);
  k_conv2 <<<2048, 256, 0, stream>>>(z1t, w2f, eb2, z2);
  k_conv3 <<<512,  256, 0, stream>>>(z2, wc3p, eb3, z3, z3h, z3l);
  k_vqp   <<<256,  256, 0, stream>>>(z3h, z3l, cbf, c2, idxb);
  k_vqf   <<<256,  256, 0, stream>>>(z3, cb, idxb, et, acc);
  k_convT1<<<2048, 256, 0, stream>>>(et, wt1f, db1, h1t);
  k_convT2<<<4096, 256, 0, stream>>>(h1t, wt2f, db2, h2t);
  k_convT3<<<8000, 256, 0, stream>>>(h2t, w3f, db3, x, out + 3, psum);
  k_fin   <<<1,    256, 0, stream>>>(acc, psum, out);
}

// Round 14
// 300.068 us; speedup vs baseline: 1.0843x; 1.0232x over previous
//
#include <hip/hip_runtime.h>

#define DEV __device__ __forceinline__
typedef unsigned short u16;
typedef __bf16 bf16x8 __attribute__((ext_vector_type(8)));
typedef float f32x4 __attribute__((ext_vector_type(4)));

DEV u16 f2bf(float f) {                      // RNE f32 -> bf16
  unsigned u = __float_as_uint(f);
  u += 0x7FFF + ((u >> 16) & 1);
  return (u16)(u >> 16);
}

// ---------------- geometry ----------------
// x    [64,3,125,125] fp32
// xp   [64,3,129,128] fp32 zero-padded
// z1t  [64,63,64,32]  bf16
// z2   [64,64,32,32]  fp32
// z3   [64,64,32,32]  fp32  + z3h/z3l [65536][64] bf16
// e_t  [64,32,32,64]  bf16  pixel-major
// h1t  [64,64,64,64]  bf16  pixel-major
// h2t  [64,128,128,32] bf16 pixel-major
// xr   [64,3,125,125] fp32

// ---------------- prep ----------------
__global__ __launch_bounds__(256) void k_prep(
    const float* __restrict__ ew1, const float* __restrict__ ew2,
    const float* __restrict__ ew3, const float* __restrict__ dw1,
    const float* __restrict__ dw2, const float* __restrict__ dw3,
    const float* __restrict__ cb,
    float* __restrict__ wc1p, float* __restrict__ wc3p,
    u16* __restrict__ w3f, float* __restrict__ c2,
    u16* __restrict__ w2f, u16* __restrict__ wt1f, u16* __restrict__ wt2f,
    u16* __restrict__ cbf) {
  int i = blockIdx.x * 256 + threadIdx.x;
  if (i < 864) {
    int cl = i & 7; int t = i >> 3; int tap = t % 9; t /= 9; int ci = t % 3; int cog = t / 3;
    wc1p[i] = ew1[((cog * 8 + cl) * 3 + ci) * 9 + tap];
  } else if (i < 4960) {
    int j = i - 864; int cl = j & 7; int t = j >> 3; int ci = t & 63; int cog = t >> 6;
    wc3p[j] = ew3[(cog * 8 + cl) * 64 + ci];
  } else if (i < 9056) {
    int j = i - 4960;                       // [hl][tp][lane][8]
    int jj = j & 7; int lane = (j >> 3) & 63; int tp = (j >> 9) & 3; int hl = j >> 11;
    int kh = tp >> 1, kw = tp & 1;
    int ci = ((lane >> 4) << 3) + jj; int co = lane & 15;
    float wv = (co < 3) ? dw3[((ci * 3 + co) * 2 + kh) * 2 + kw] : 0.f;
    u16 hi = f2bf(wv);
    if (hl == 0) w3f[j] = hi;
    else         w3f[j] = f2bf(wv - __uint_as_float((unsigned)hi << 16));
  } else if (i < 9568) {
    int k = i - 9056;
    const float4* c4 = (const float4*)(cb + (k << 6));
    float s = 0.f;
    #pragma unroll
    for (int q = 0; q < 16; ++q) { float4 v = c4[q]; s += v.x*v.x + v.y*v.y + v.z*v.z + v.w*v.w; }
    c2[k] = s;
  } else if (i < 28000) {
    int j = i - 9568;                       // [kt][nf][lane][8]
    int jj = j & 7; int lane = (j >> 3) & 63; int nf = (j >> 9) & 3; int kt = j >> 11;
    int kh = kt / 3, kw = kt % 3;
    int ci = ((lane >> 4) << 3) + jj; int co = (nf << 4) + (lane & 15);
    w2f[j] = f2bf(ew2[((co * 32 + ci) * 3 + kh) * 3 + kw]);
  } else if (i < 64864) {
    int j = i - 28000;                      // [kt][s][nf][lane][8]
    int jj = j & 7; int lane = (j >> 3) & 63; int nf = (j >> 9) & 3; int s = (j >> 11) & 1; int kt = j >> 12;
    int kh = kt / 3, kw = kt % 3;
    int ci = (s << 5) + ((lane >> 4) << 3) + jj; int co = (nf << 4) + (lane & 15);
    wt1f[j] = f2bf(dw1[((ci * 64 + co) * 3 + kh) * 3 + kw]);
  } else if (i < 83296) {
    int j = i - 64864;                      // [kt][s][nf][lane][8]
    int jj = j & 7; int lane = (j >> 3) & 63; int nf = (j >> 9) & 1; int s = (j >> 10) & 1; int kt = j >> 11;
    int kh = kt / 3, kw = kt % 3;
    int ci = (s << 5) + ((lane >> 4) << 3) + jj; int co = (nf << 4) + (lane & 15);
    wt2f[j] = f2bf(dw2[((ci * 32 + co) * 3 + kh) * 3 + kw]);
  } else if (i < 148832) {
    int j = i - 83296;                      // [hl][ks][nt][lane][8]
    int jj = j & 7; int lane = (j >> 3) & 63; int nt = (j >> 9) & 31; int ks = (j >> 14) & 1; int hl = j >> 15;
    int ci = (ks << 5) + ((lane >> 4) << 3) + jj;
    int code = (nt << 4) + (lane & 15);
    float v = cb[(code << 6) + ci];
    u16 hi = f2bf(v);
    cbf[j] = hl ? f2bf(v - __uint_as_float((unsigned)hi << 16)) : hi;
  }
}

// ---------------- pad: x -> xp [64*3][129][128], zero borders ----------------
__global__ __launch_bounds__(256) void k_pad(
    const float* __restrict__ x, float* __restrict__ xp) {
  int idx = blockIdx.x * 256 + threadIdx.x;
  int c4 = idx & 31;
  int r  = (idx >> 5) % 129;
  int cbp = (idx >> 5) / 129;
  int ih = r - 1;
  float4 v = make_float4(0.f, 0.f, 0.f, 0.f);
  if ((unsigned)ih < 125u) {
    const float* rp = x + (cbp * 125 + ih) * 125;
    int iw0 = c4 * 4 - 1;
    if (iw0 >= 0)        v.x = rp[iw0];
    if (iw0 + 1 < 125)   v.y = rp[iw0 + 1];
    if (iw0 + 2 < 125)   v.z = rp[iw0 + 2];
    if (iw0 + 3 < 125)   v.w = rp[iw0 + 3];
  }
  *(float4*)(xp + (cbp * 129 + r) * 128 + c4 * 4) = v;
}

// ---------------- conv1: padded input, all-co blocks, LDS wide stores ----------------
__global__ __launch_bounds__(256) void k_conv1(
    const float* __restrict__ xp, const float* __restrict__ wp,
    const float* __restrict__ bias, u16* __restrict__ z1t) {
  __shared__ u16 st[256 * 34];
  int t = threadIdx.x;
  int slab = blockIdx.x & 15, b = blockIdx.x >> 4;   // grid 1024
  int tx = t & 15, ty = (t >> 4) & 3, cg = t >> 6;
  int oh = slab * 4 + ty;
  int co0 = cg * 8;
  const float* wcg = wp + cg * 216;
  float acc[8][4];
  #pragma unroll
  for (int c = 0; c < 8; ++c) {
    float bv = bias[co0 + c];
    #pragma unroll
    for (int s = 0; s < 4; ++s) acc[c][s] = bv;
  }
  #pragma unroll
  for (int ci = 0; ci < 3; ++ci) {
    #pragma unroll
    for (int kh = 0; kh < 3; ++kh) {
      const float* rp = xp + ((b * 3 + ci) * 129 + (2 * oh + kh)) * 128 + 8 * tx;
      float4 qa = *(const float4*)rp;
      float4 qb = *(const float4*)(rp + 4);
      float v8 = rp[8];
      float v[9] = {qa.x, qa.y, qa.z, qa.w, qb.x, qb.y, qb.z, qb.w, v8};
      #pragma unroll
      for (int kw = 0; kw < 3; ++kw) {
        const float* wq = wcg + (ci * 9 + kh * 3 + kw) * 8;
        float4 wa = *(const float4*)wq;
        float4 wb = *(const float4*)(wq + 4);
        float w8[8] = {wa.x, wa.y, wa.z, wa.w, wb.x, wb.y, wb.z, wb.w};
        #pragma unroll
        for (int s = 0; s < 4; ++s) {
          float in = v[2 * s + kw];
          #pragma unroll
          for (int c = 0; c < 8; ++c) acc[c][s] = fmaf(in, w8[c], acc[c][s]);
        }
      }
    }
  }
  #pragma unroll
  for (int s = 0; s < 4; ++s) {
    bool wok = (tx * 4 + s) < 63;
    unsigned p0 = 0, p1 = 0, p2 = 0, p3 = 0;
    if (wok) {
      p0 = f2bf(fmaxf(acc[0][s], 0.f)) | ((unsigned)f2bf(fmaxf(acc[1][s], 0.f)) << 16);
      p1 = f2bf(fmaxf(acc[2][s], 0.f)) | ((unsigned)f2bf(fmaxf(acc[3][s], 0.f)) << 16);
      p2 = f2bf(fmaxf(acc[4][s], 0.f)) | ((unsigned)f2bf(fmaxf(acc[5][s], 0.f)) << 16);
      p3 = f2bf(fmaxf(acc[6][s], 0.f)) | ((unsigned)f2bf(fmaxf(acc[7][s], 0.f)) << 16);
    }
    int lpix = tx * 16 + ty * 4 + s;
    *(uint4*)&st[lpix * 34 + co0] = make_uint4(p0, p1, p2, p3);
  }
  __syncthreads();
  {
    int p = t;
    int ow = (p >> 4) * 4 + (p & 3);
    int ohl = (p >> 2) & 3;
    int oho = slab * 4 + ohl;
    if (oho < 63) {
      const u16* lp = &st[p * 34];
      uint4 a0 = *(const uint4*)(lp);
      uint4 a1 = *(const uint4*)(lp + 8);
      uint4 a2 = *(const uint4*)(lp + 16);
      uint4 a3 = *(const uint4*)(lp + 24);
      uint4* gp = (uint4*)(z1t + ((b * 63 + oho) * 64 + ow) * 32);
      gp[0] = a0; gp[1] = a1; gp[2] = a2; gp[3] = a3;
    }
  }
}

// ---------------- conv2: MFMA, block=(b,oh), waves=(xt2, ch2) ----------------
__global__ __launch_bounds__(256) void k_conv2(
    const u16* __restrict__ z1t, const u16* __restrict__ wf,
    const float* __restrict__ bias, float* __restrict__ z2) {
  int t = threadIdx.x;
  int lane = t & 63, wv = t >> 6;
  int n = lane & 15, q = lane >> 4;
  int oh = blockIdx.x & 31, b = blockIdx.x >> 5;   // grid 2048
  int xt = wv & 1, ch = wv >> 1;
  int xA = xt * 16 + n;
  f32x4 acc[2] = {{0,0,0,0},{0,0,0,0}};
  #pragma unroll
  for (int kh = 0; kh < 3; ++kh) {
    int ih = 2 * oh - 1 + kh;
    bool yok = (unsigned)ih < 63u;
    #pragma unroll
    for (int kw = 0; kw < 3; ++kw) {
      int iw = 2 * xA - 1 + kw;
      bool ok = yok && (iw >= 0);
      bf16x8 a = {};
      if (ok) a = *(const bf16x8*)(z1t + ((b * 63 + ih) * 64 + iw) * 32 + q * 8);
      int kt = kh * 3 + kw;
      const u16* wb = wf + ((kt << 2) + (ch << 1)) * 512 + lane * 8;
      bf16x8 b0 = *(const bf16x8*)wb;
      bf16x8 b1 = *(const bf16x8*)(wb + 512);
      acc[0] = __builtin_amdgcn_mfma_f32_16x16x32_bf16(a, b0, acc[0], 0, 0, 0);
      acc[1] = __builtin_amdgcn_mfma_f32_16x16x32_bf16(a, b1, acc[1], 0, 0, 0);
    }
  }
  #pragma unroll
  for (int j = 0; j < 2; ++j) {
    int co = ((ch << 1) + j) * 16 + n;
    float bv = bias[co];
    float4 rv = make_float4(fmaxf(acc[j][0] + bv, 0.f), fmaxf(acc[j][1] + bv, 0.f),
                            fmaxf(acc[j][2] + bv, 0.f), fmaxf(acc[j][3] + bv, 0.f));
    *(float4*)(z2 + ((b * 64 + co) * 32 + oh) * 32 + xt * 16 + q * 4) = rv;
  }
}

// ---------------- conv3 (1x1): fp32, + LDS transpose to pixel-major hi/lo ----------------
__global__ __launch_bounds__(256) void k_conv3(
    const float* __restrict__ in, const float* __restrict__ wp,
    const float* __restrict__ bias, float* __restrict__ z3,
    u16* __restrict__ z3h, u16* __restrict__ z3l) {
  __shared__ u16 lh[128 * 72];
  __shared__ u16 ll[128 * 72];
  int t = threadIdx.x;
  int pxg = blockIdx.x & 7; int b = blockIdx.x >> 3;   // grid 512
  int pxi = t & 31, cog = t >> 5;
  int px0 = pxg * 128 + pxi * 4;
  const float* wcg = wp + cog * 512;
  int co0 = cog * 8;
  float acc[8][4];
  #pragma unroll
  for (int c = 0; c < 8; ++c) {
    float bv = bias[co0 + c];
    #pragma unroll
    for (int s = 0; s < 4; ++s) acc[c][s] = bv;
  }
  const float* ip = in + (b << 16) + px0;
  for (int ci = 0; ci < 64; ++ci) {
    float4 v = *(const float4*)(ip + (ci << 10));
    float4 wa = *(const float4*)(wcg + ci * 8);
    float4 wb = *(const float4*)(wcg + ci * 8 + 4);
    float w8[8] = {wa.x, wa.y, wa.z, wa.w, wb.x, wb.y, wb.z, wb.w};
    #pragma unroll
    for (int c = 0; c < 8; ++c) {
      acc[c][0] = fmaf(v.x, w8[c], acc[c][0]);
      acc[c][1] = fmaf(v.y, w8[c], acc[c][1]);
      acc[c][2] = fmaf(v.z, w8[c], acc[c][2]);
      acc[c][3] = fmaf(v.w, w8[c], acc[c][3]);
    }
  }
  float* op = z3 + ((b << 6) + co0) * 1024 + px0;
  #pragma unroll
  for (int c = 0; c < 8; ++c)
    *(float4*)(op + (c << 10)) = make_float4(acc[c][0], acc[c][1], acc[c][2], acc[c][3]);
  #pragma unroll
  for (int s = 0; s < 4; ++s) {
    unsigned h[4], l[4];
    #pragma unroll
    for (int g = 0; g < 4; ++g) {
      float v0 = acc[2 * g][s], v1 = acc[2 * g + 1][s];
      u16 h0 = f2bf(v0), h1 = f2bf(v1);
      u16 l0 = f2bf(v0 - __uint_as_float((unsigned)h0 << 16));
      u16 l1 = f2bf(v1 - __uint_as_float((unsigned)h1 << 16));
      h[g] = h0 | ((unsigned)h1 << 16);
      l[g] = l0 | ((unsigned)l1 << 16);
    }
    int la = (pxi * 4 + s) * 72 + co0;
    *(uint4*)&lh[la] = make_uint4(h[0], h[1], h[2], h[3]);
    *(uint4*)&ll[la] = make_uint4(l[0], l[1], l[2], l[3]);
  }
  __syncthreads();
  {
    int p = t >> 1, half = t & 1;
    int la = p * 72 + half * 32;
    uint4 h0 = *(uint4*)&lh[la],      h1 = *(uint4*)&lh[la + 8];
    uint4 h2 = *(uint4*)&lh[la + 16], h3 = *(uint4*)&lh[la + 24];
    uint4 l0 = *(uint4*)&ll[la],      l1 = *(uint4*)&ll[la + 8];
    uint4 l2 = *(uint4*)&ll[la + 16], l3 = *(uint4*)&ll[la + 24];
    long gp = ((long)b * 1024 + pxg * 128 + p) * 64 + half * 32;
    uint4* oh = (uint4*)(z3h + gp);
    uint4* ol = (uint4*)(z3l + gp);
    oh[0] = h0; oh[1] = h1; oh[2] = h2; oh[3] = h3;
    ol[0] = l0; ol[1] = l1; ol[2] = l2; ol[3] = l3;
  }
}

// ---------------- VQ argmin: MFMA hi/lo, 64 px/wave x 512 codes ----------------
__global__ __launch_bounds__(256) void k_vqp(
    const u16* __restrict__ z3h, const u16* __restrict__ z3l,
    const u16* __restrict__ cbf, const float* __restrict__ c2v,
    int* __restrict__ idxb) {
  int t = threadIdx.x;
  int lane = t & 63, wv = t >> 6;
  int n = lane & 15, q = lane >> 4;
  int p0 = (blockIdx.x * 4 + wv) * 64;               // grid 256
  bf16x8 Ah[4][2], Al[4][2];
  #pragma unroll
  for (int mt = 0; mt < 4; ++mt) {
    const u16* ap = z3h + (p0 + mt * 16 + n) * 64 + q * 8;
    const u16* al = z3l + (p0 + mt * 16 + n) * 64 + q * 8;
    Ah[mt][0] = *(const bf16x8*)ap;  Ah[mt][1] = *(const bf16x8*)(ap + 32);
    Al[mt][0] = *(const bf16x8*)al;  Al[mt][1] = *(const bf16x8*)(al + 32);
  }
  float bs[4][4]; int bix[4][4];
  #pragma unroll
  for (int mt = 0; mt < 4; ++mt)
    #pragma unroll
    for (int r = 0; r < 4; ++r) { bs[mt][r] = 3.4e38f; bix[mt][r] = 0; }
  for (int nt = 0; nt < 32; ++nt) {
    const u16* bp = cbf + lane * 8;
    bf16x8 Bh0 = *(const bf16x8*)(bp + (nt << 9));
    bf16x8 Bh1 = *(const bf16x8*)(bp + ((32 + nt) << 9));
    bf16x8 Bl0 = *(const bf16x8*)(bp + ((64 + nt) << 9));
    bf16x8 Bl1 = *(const bf16x8*)(bp + ((96 + nt) << 9));
    float c2 = c2v[(nt << 4) + n];
    #pragma unroll
    for (int mt = 0; mt < 4; ++mt) {
      f32x4 acc = {0.f, 0.f, 0.f, 0.f};
      acc = __builtin_amdgcn_mfma_f32_16x16x32_bf16(Ah[mt][0], Bh0, acc, 0, 0, 0);
      acc = __builtin_amdgcn_mfma_f32_16x16x32_bf16(Ah[mt][1], Bh1, acc, 0, 0, 0);
      acc = __builtin_amdgcn_mfma_f32_16x16x32_bf16(Al[mt][0], Bh0, acc, 0, 0, 0);
      acc = __builtin_amdgcn_mfma_f32_16x16x32_bf16(Al[mt][1], Bh1, acc, 0, 0, 0);
      acc = __builtin_amdgcn_mfma_f32_16x16x32_bf16(Ah[mt][0], Bl0, acc, 0, 0, 0);
      acc = __builtin_amdgcn_mfma_f32_16x16x32_bf16(Ah[mt][1], Bl1, acc, 0, 0, 0);
      int idx = (nt << 4) + n;
      #pragma unroll
      for (int r = 0; r < 4; ++r) {
        float sc = fmaf(-2.f, acc[r], c2);
        if (sc < bs[mt][r]) { bs[mt][r] = sc; bix[mt][r] = idx; }
      }
    }
  }
  #pragma unroll
  for (int off = 8; off > 0; off >>= 1) {
    #pragma unroll
    for (int mt = 0; mt < 4; ++mt)
      #pragma unroll
      for (int r = 0; r < 4; ++r) {
        float os = __shfl_xor(bs[mt][r], off, 16);
        int oi = __shfl_xor(bix[mt][r], off, 16);
        if (os < bs[mt][r] || (os == bs[mt][r] && oi < bix[mt][r])) {
          bs[mt][r] = os; bix[mt][r] = oi;
        }
      }
  }
  if (n == 0) {
    #pragma unroll
    for (int mt = 0; mt < 4; ++mt)
      #pragma unroll
      for (int r = 0; r < 4; ++r)
        idxb[p0 + mt * 16 + q * 4 + r] = bix[mt][r];
  }
}

// ---------------- VQ finalize: gather, write e_t bf16, loss ----------------
__global__ __launch_bounds__(256) void k_vqf(
    const float* __restrict__ z3, const float* __restrict__ cb,
    const int* __restrict__ idxb, u16* __restrict__ et,
    float* __restrict__ acc) {
  int n = blockIdx.x * 256 + threadIdx.x;  // 65536
  int bi = idxb[n];
  int b = n >> 10, hw = n & 1023;
  const float* zp = z3 + (b << 16) + hw;
  uint2* ep = (uint2*)(et + (n << 6));
  const float4* cq = (const float4*)(cb + (bi << 6));
  float lsum = 0.f;
  #pragma unroll
  for (int i = 0; i < 16; ++i) {
    float4 c = cq[i];
    float zv, df;
    zv = zp[(4*i+0) << 10]; df = c.x - zv; lsum = fmaf(df, df, lsum);
    zv = zp[(4*i+1) << 10]; df = c.y - zv; lsum = fmaf(df, df, lsum);
    zv = zp[(4*i+2) << 10]; df = c.z - zv; lsum = fmaf(df, df, lsum);
    zv = zp[(4*i+3) << 10]; df = c.w - zv; lsum = fmaf(df, df, lsum);
    ep[i] = make_uint2(f2bf(c.x) | ((unsigned)f2bf(c.y) << 16),
                       f2bf(c.z) | ((unsigned)f2bf(c.w) << 16));
  }
  __shared__ float red[256];
  red[threadIdx.x] = lsum; __syncthreads();
  #pragma unroll
  for (int s = 128; s > 0; s >>= 1) {
    if (threadIdx.x < s) red[threadIdx.x] += red[threadIdx.x + s];
    __syncthreads();
  }
  if (threadIdx.x == 0) atomicAdd(acc + 0, red[0]);
}

// ---------------- convT1: cog-split, LDS weights, 4 y-pairs/block loop ----------------
// block = (b, yg8, cog2). waves = (yw2, xt2); iter 2 -> 4 pairs. grid 1024.
__global__ __launch_bounds__(256) void k_convT1(
    const u16* __restrict__ et, const u16* __restrict__ wf,
    const float* __restrict__ bias, u16* __restrict__ h1t) {
  __shared__ u16 wl[36 * 512];      // 36864 B
  __shared__ u16 st[4][64 * 34];    // 17408 B
  int t = threadIdx.x;
  int lane = t & 63, wv = t >> 6;
  int yw = wv & 1, xt = wv >> 1;
  int cog = blockIdx.x & 1;
  int yg = (blockIdx.x >> 1) & 7;
  int b = blockIdx.x >> 4;           // grid 1024
  {
    const uint4* gw = (const uint4*)wf;
    uint4* lw = (uint4*)wl;
    #pragma unroll
    for (int k = 0; k < 9; ++k) {
      int i = t + 256 * k;
      int slot = i >> 6, within = i & 63;
      int kt = slot >> 2, j = (slot >> 1) & 1, ks = slot & 1;
      int goff = (kt << 12) + (((ks << 2) + (cog << 1) + j) << 9);
      lw[i] = gw[(goff >> 3) + within];
    }
  }
  int n = lane & 15, q = lane >> 4;
  int m = xt * 16 + n;
  __syncthreads();
  for (int iter = 0; iter < 2; ++iter) {
    int y = yg * 4 + iter * 2 + yw;
    const u16* base0 = et + (((b * 32 + y) * 32) << 6) + q * 8;
    bf16x8 P00a, P00b, P01a = {}, P01b = {}, P10a = {}, P10b = {}, P11a = {}, P11b = {};
    { const u16* p = base0 + (m << 6); P00a = *(const bf16x8*)p; P00b = *(const bf16x8*)(p + 32); }
    if (m + 1 < 32) { const u16* p = base0 + ((m + 1) << 6); P01a = *(const bf16x8*)p; P01b = *(const bf16x8*)(p + 32); }
    if (y + 1 < 32) {
      const u16* base1 = base0 + (32 << 6);
      { const u16* p = base1 + (m << 6); P10a = *(const bf16x8*)p; P10b = *(const bf16x8*)(p + 32); }
      if (m + 1 < 32) { const u16* p = base1 + ((m + 1) << 6); P11a = *(const bf16x8*)p; P11b = *(const bf16x8*)(p + 32); }
    }
    f32x4 accE[2][2] = {};  // [j][pwi]
    f32x4 accO[2][2] = {};
    #pragma unroll
    for (int kw = 0; kw < 3; ++kw) {
      int pwi = (kw == 1) ? 0 : 1;
      bf16x8 A0a = (kw == 0) ? P01a : P00a;
      bf16x8 A0b = (kw == 0) ? P01b : P00b;
      bf16x8 A1a = (kw == 0) ? P11a : P10a;
      bf16x8 A1b = (kw == 0) ? P11b : P10b;
      #pragma unroll
      for (int j = 0; j < 2; ++j) {
        const u16* wE  = wl + ((((3 + kw) << 2) + (j << 1)) << 9) + lane * 8;
        const u16* wO0 = wl + (((kw << 2) + (j << 1)) << 9) + lane * 8;
        const u16* wO2 = wl + ((((6 + kw) << 2) + (j << 1)) << 9) + lane * 8;
        bf16x8 bE0 = *(const bf16x8*)wE;
        bf16x8 bE1 = *(const bf16x8*)(wE + 512);
        accE[j][pwi] = __builtin_amdgcn_mfma_f32_16x16x32_bf16(A0a, bE0, accE[j][pwi], 0, 0, 0);
        accE[j][pwi] = __builtin_amdgcn_mfma_f32_16x16x32_bf16(A0b, bE1, accE[j][pwi], 0, 0, 0);
        bf16x8 bO00 = *(const bf16x8*)wO0;
        bf16x8 bO01 = *(const bf16x8*)(wO0 + 512);
        accO[j][pwi] = __builtin_amdgcn_mfma_f32_16x16x32_bf16(A1a, bO00, accO[j][pwi], 0, 0, 0);
        accO[j][pwi] = __builtin_amdgcn_mfma_f32_16x16x32_bf16(A1b, bO01, accO[j][pwi], 0, 0, 0);
        bf16x8 bO20 = *(const bf16x8*)wO2;
        bf16x8 bO21 = *(const bf16x8*)(wO2 + 512);
        accO[j][pwi] = __builtin_amdgcn_mfma_f32_16x16x32_bf16(A0a, bO20, accO[j][pwi], 0, 0, 0);
        accO[j][pwi] = __builtin_amdgcn_mfma_f32_16x16x32_bf16(A0b, bO21, accO[j][pwi], 0, 0, 0);
      }
    }
    #pragma unroll
    for (int j = 0; j < 2; ++j) {
      int col = j * 16 + n;
      float bv = bias[cog * 32 + col];
      #pragma unroll
      for (int pw = 0; pw < 2; ++pw)
        #pragma unroll
        for (int r = 0; r < 4; ++r) {
          int ow = 2 * (xt * 16 + q * 4 + r) + pw;
          st[yw * 2 + 0][ow * 34 + col] = f2bf(fmaxf(accE[j][pw][r] + bv, 0.f));
          st[yw * 2 + 1][ow * 34 + col] = f2bf(fmaxf(accO[j][pw][r] + bv, 0.f));
        }
    }
    __syncthreads();
    {
      int row = t >> 6, ow = t & 63;   // 4 rows x 64 ow
      const u16* lp = &st[row][ow * 34];
      uint4* gp = (uint4*)(h1t + (((b * 64 + yg * 8 + iter * 4 + row) * 64 + ow) << 6) + cog * 32);
      gp[0] = *(const uint4*)(lp);
      gp[1] = *(const uint4*)(lp + 8);
      gp[2] = *(const uint4*)(lp + 16);
      gp[3] = *(const uint4*)(lp + 24);
    }
    __syncthreads();
  }
}

// ---------------- convT2: LDS weights, 4 y-pairs/block loop ----------------
// block = (b, yg16). waves = xt4; loop yp 0..3. grid 1024.
__global__ __launch_bounds__(256) void k_convT2(
    const u16* __restrict__ h1t, const u16* __restrict__ wf,
    const float* __restrict__ bias, u16* __restrict__ h2t) {
  __shared__ u16 wl[18432];         // 36864 B
  __shared__ u16 st[2][128 * 34];   // 17408 B
  int t = threadIdx.x;
  int lane = t & 63, xt = t >> 6;
  int n = lane & 15, q = lane >> 4;
  int yg = blockIdx.x & 15, b = blockIdx.x >> 4;   // grid 1024
  {
    const uint4* gw = (const uint4*)wf;
    uint4* lw = (uint4*)wl;
    #pragma unroll
    for (int k = 0; k < 9; ++k) lw[t + 256 * k] = gw[t + 256 * k];
  }
  int m = xt * 16 + n;
  __syncthreads();
  for (int yp = 0; yp < 4; ++yp) {
    int y = yg * 4 + yp;
    const u16* base0 = h1t + (((b * 64 + y) * 64) << 6) + q * 8;
    bf16x8 P00a, P00b, P01a = {}, P01b = {}, P10a = {}, P10b = {}, P11a = {}, P11b = {};
    { const u16* p = base0 + (m << 6); P00a = *(const bf16x8*)p; P00b = *(const bf16x8*)(p + 32); }
    if (m + 1 < 64) { const u16* p = base0 + ((m + 1) << 6); P01a = *(const bf16x8*)p; P01b = *(const bf16x8*)(p + 32); }
    if (y + 1 < 64) {
      const u16* base1 = base0 + (64 << 6);
      { const u16* p = base1 + (m << 6); P10a = *(const bf16x8*)p; P10b = *(const bf16x8*)(p + 32); }
      if (m + 1 < 64) { const u16* p = base1 + ((m + 1) << 6); P11a = *(const bf16x8*)p; P11b = *(const bf16x8*)(p + 32); }
    }
    f32x4 accE[2][2] = {};  // [nf][pwi]
    f32x4 accO[2][2] = {};
    #pragma unroll
    for (int kw = 0; kw < 3; ++kw) {
      int pwi = (kw == 1) ? 0 : 1;
      bf16x8 A0a = (kw == 0) ? P01a : P00a;
      bf16x8 A0b = (kw == 0) ? P01b : P00b;
      bf16x8 A1a = (kw == 0) ? P11a : P10a;
      bf16x8 A1b = (kw == 0) ? P11b : P10b;
      const u16* wbE = wl + ((3 + kw) << 11) + lane * 8;
      const u16* wbO0 = wl + (kw << 11) + lane * 8;
      const u16* wbO2 = wl + ((6 + kw) << 11) + lane * 8;
      #pragma unroll
      for (int nf = 0; nf < 2; ++nf) {
        bf16x8 bE0 = *(const bf16x8*)(wbE + nf * 512);
        bf16x8 bE1 = *(const bf16x8*)(wbE + (2 + nf) * 512);
        accE[nf][pwi] = __builtin_amdgcn_mfma_f32_16x16x32_bf16(A0a, bE0, accE[nf][pwi], 0, 0, 0);
        accE[nf][pwi] = __builtin_amdgcn_mfma_f32_16x16x32_bf16(A0b, bE1, accE[nf][pwi], 0, 0, 0);
        bf16x8 bO00 = *(const bf16x8*)(wbO0 + nf * 512);
        bf16x8 bO01 = *(const bf16x8*)(wbO0 + (2 + nf) * 512);
        accO[nf][pwi] = __builtin_amdgcn_mfma_f32_16x16x32_bf16(A1a, bO00, accO[nf][pwi], 0, 0, 0);
        accO[nf][pwi] = __builtin_amdgcn_mfma_f32_16x16x32_bf16(A1b, bO01, accO[nf][pwi], 0, 0, 0);
        bf16x8 bO20 = *(const bf16x8*)(wbO2 + nf * 512);
        bf16x8 bO21 = *(const bf16x8*)(wbO2 + (2 + nf) * 512);
        accO[nf][pwi] = __builtin_amdgcn_mfma_f32_16x16x32_bf16(A0a, bO20, accO[nf][pwi], 0, 0, 0);
        accO[nf][pwi] = __builtin_amdgcn_mfma_f32_16x16x32_bf16(A0b, bO21, accO[nf][pwi], 0, 0, 0);
      }
    }
    #pragma unroll
    for (int nf = 0; nf < 2; ++nf) {
      int co = nf * 16 + n;
      float bv = bias[co];
      #pragma unroll
      for (int pw = 0; pw < 2; ++pw)
        #pragma unroll
        for (int r = 0; r < 4; ++r) {
          int ow = 2 * (xt * 16 + q * 4 + r) + pw;
          st[0][ow * 34 + co] = f2bf(fmaxf(accE[nf][pw][r] + bv, 0.f));
          st[1][ow * 34 + co] = f2bf(fmaxf(accO[nf][pw][r] + bv, 0.f));
        }
    }
    __syncthreads();
    {
      int ow = t >> 1, sg = t & 1;
      #pragma unroll
      for (int l = 0; l < 2; ++l) {
        const u16* lp = &st[l][ow * 34 + sg * 16];
        unsigned w0 = *(const unsigned*)(lp + 0), w1 = *(const unsigned*)(lp + 2);
        unsigned w2 = *(const unsigned*)(lp + 4), w3 = *(const unsigned*)(lp + 6);
        unsigned w4 = *(const unsigned*)(lp + 8), w5 = *(const unsigned*)(lp + 10);
        unsigned w6 = *(const unsigned*)(lp + 12), w7 = *(const unsigned*)(lp + 14);
        uint4* gp = (uint4*)(h2t + ((((b * 128 + yg * 8 + yp * 2 + l) * 128) + ow) << 5) + sg * 16);
        gp[0] = make_uint4(w0, w1, w2, w3);
        gp[1] = make_uint4(w4, w5, w6, w7);
      }
    }
    __syncthreads();
  }
}

// ---------------- convT3 + recon loss: MFMA, per-block partial sums ----------------
__global__ __launch_bounds__(256) void k_convT3(
    const u16* __restrict__ h2t, const u16* __restrict__ w3f,
    const float* __restrict__ bias, const float* __restrict__ x,
    float* __restrict__ xr, float* __restrict__ psum) {
  int t = threadIdx.x;
  int lane = t & 63, wv = t >> 6;
  int n = lane & 15, q = lane >> 4;
  int oh = blockIdx.x % 125, b = blockIdx.x / 125;   // grid 8000
  const u16* wbp = w3f + lane * 8;
  bf16x8 Bh0 = *(const bf16x8*)(wbp);
  bf16x8 Bh1 = *(const bf16x8*)(wbp + 512);
  bf16x8 Bh2 = *(const bf16x8*)(wbp + 1024);
  bf16x8 Bh3 = *(const bf16x8*)(wbp + 1536);
  bf16x8 Bl0 = *(const bf16x8*)(wbp + 2048);
  bf16x8 Bl1 = *(const bf16x8*)(wbp + 2560);
  bf16x8 Bl2 = *(const bf16x8*)(wbp + 3072);
  bf16x8 Bl3 = *(const bf16x8*)(wbp + 3584);
  const u16* row1 = h2t + (((long)b * 128 + (oh + 1)) << 7) * 32 + q * 8;
  const u16* row2 = row1 + 4096;
  float bv = (n < 3) ? bias[n] : 0.f;
  float lsum = 0.f;
  #pragma unroll
  for (int ti = 0; ti < 2; ++ti) {
    int tt = wv + ti * 4;
    int c1 = tt * 16 + n + 1;
    int c2 = c1 + 1;
    bf16x8 a11 = {}, a12 = {}, a21 = {}, a22 = {};
    if (c1 < 128) { a11 = *(const bf16x8*)(row1 + (c1 << 5));
                    a21 = *(const bf16x8*)(row2 + (c1 << 5)); }
    if (c2 < 128) { a12 = *(const bf16x8*)(row1 + (c2 << 5));
                    a22 = *(const bf16x8*)(row2 + (c2 << 5)); }
    f32x4 acc = {0.f, 0.f, 0.f, 0.f};
    acc = __builtin_amdgcn_mfma_f32_16x16x32_bf16(a11, Bh3, acc, 0, 0, 0);
    acc = __builtin_amdgcn_mfma_f32_16x16x32_bf16(a12, Bh2, acc, 0, 0, 0);
    acc = __builtin_amdgcn_mfma_f32_16x16x32_bf16(a21, Bh1, acc, 0, 0, 0);
    acc = __builtin_amdgcn_mfma_f32_16x16x32_bf16(a22, Bh0, acc, 0, 0, 0);
    acc = __builtin_amdgcn_mfma_f32_16x16x32_bf16(a11, Bl3, acc, 0, 0, 0);
    acc = __builtin_amdgcn_mfma_f32_16x16x32_bf16(a12, Bl2, acc, 0, 0, 0);
    acc = __builtin_amdgcn_mfma_f32_16x16x32_bf16(a21, Bl1, acc, 0, 0, 0);
    acc = __builtin_amdgcn_mfma_f32_16x16x32_bf16(a22, Bl0, acc, 0, 0, 0);
    if (n < 3) {
      int ow0 = tt * 16 + q * 4;
      int o = b * 46875 + n * 15625 + oh * 125 + ow0;
      if (ow0 + 3 < 125) {
        float4 v = make_float4(acc[0] + bv, acc[1] + bv, acc[2] + bv, acc[3] + bv);
        float4 xv = *(const float4*)(x + o);
        *(float4*)(xr + o) = v;
        float d0 = v.x - xv.x, d1 = v.y - xv.y, d2 = v.z - xv.z, d3 = v.w - xv.w;
        lsum += d0 * d0 + d1 * d1 + d2 * d2 + d3 * d3;
      } else {
        #pragma unroll
        for (int r = 0; r < 4; ++r) {
          if (ow0 + r < 125) {
            float v = acc[r] + bv;
            xr[o + r] = v;
            float d = v - x[o + r];
            lsum = fmaf(d, d, lsum);
          }
        }
      }
    }
  }
  __shared__ float red[256];
  red[t] = lsum; __syncthreads();
  #pragma unroll
  for (int s = 128; s > 0; s >>= 1) {
    if (t < s) red[t] += red[t + s];
    __syncthreads();
  }
  if (t == 0) psum[blockIdx.x] = red[0];
}

// ---------------- finalize: reduce 8000 partials + vq loss ----------------
__global__ __launch_bounds__(256) void k_fin(
    const float* __restrict__ acc, const float* __restrict__ psum,
    float* __restrict__ out) {
  int t = threadIdx.x;
  float s = 0.f;
  for (int i = t; i < 8000; i += 256) s += psum[i];
  __shared__ float red[256];
  red[t] = s; __syncthreads();
  #pragma unroll
  for (int k = 128; k > 0; k >>= 1) {
    if (t < k) red[t] += red[t + k];
    __syncthreads();
  }
  if (t == 0) {
    float eq  = 1.25f * acc[0] / 4194304.0f;
    float rec = red[0];
    out[0] = eq + rec;
    out[1] = eq;
    out[2] = rec;
  }
}

extern "C" void kernel_launch(void* const* d_in, const int* in_sizes, int n_in,
                              void* d_out, int out_size, void* d_ws, size_t ws_size,
                              hipStream_t stream) {
  (void)in_sizes; (void)n_in; (void)out_size; (void)ws_size;
  const float* x   = (const float*)d_in[0];
  const float* ew1 = (const float*)d_in[1];
  const float* eb1 = (const float*)d_in[2];
  const float* ew2 = (const float*)d_in[3];
  const float* eb2 = (const float*)d_in[4];
  const float* ew3 = (const float*)d_in[5];
  const float* eb3 = (const float*)d_in[6];
  const float* cb  = (const float*)d_in[7];
  const float* dw1 = (const float*)d_in[8];
  const float* db1 = (const float*)d_in[9];
  const float* dw2 = (const float*)d_in[10];
  const float* db2 = (const float*)d_in[11];
  const float* dw3 = (const float*)d_in[12];
  const float* db3 = (const float*)d_in[13];
  float* out = (float*)d_out;
  char*  ws  = (char*)d_ws;

  float*  acc  = (float*)(ws + 0);
  float*  c2   = (float*)(ws + 256);
  float*  wc1p = (float*)(ws + 4096);
  float*  wc3p = (float*)(ws + 8192);
  u16*    w3f  = (u16*)  (ws + 24576);
  u16*    w2f  = (u16*)  (ws + 36864);
  u16*    wt1f = (u16*)  (ws + 73728);
  u16*    wt2f = (u16*)  (ws + 147456);
  float*  psum = (float*)(ws + 184320);
  u16*    cbf  = (u16*)  (ws + 262144);
  u16*    z1t  = (u16*)  (ws + 1048576);
  float*  z2   = (float*)(ws + 18874368);
  float*  z3   = (float*)(ws + 35651584);
  int*    idxb = (int*)  (ws + 52428800);
  u16*    et   = (u16*)  (ws + 54525952);
  u16*    h1t  = (u16*)  (ws + 1048576);
  u16*    h2t  = (u16*)  (ws + 67108864);
  u16*    z3h  = (u16*)  (ws + 134217728);
  u16*    z3l  = (u16*)  (ws + 142606336);
  float*  xp   = (float*)(ws + 150994944);

  hipMemsetAsync(acc, 0, 64, stream);
  k_prep  <<<582,  256, 0, stream>>>(ew1, ew2, ew3, dw1, dw2, dw3, cb,
                                     wc1p, wc3p, w3f, c2, w2f, wt1f, wt2f, cbf);
  k_pad   <<<3096, 256, 0, stream>>>(x, xp);
  k_conv1 <<<1024, 256, 0, stream>>>(xp, wc1p, eb1, z1t);
  k_conv2 <<<2048, 256, 0, stream>>>(z1t, w2f, eb2, z2);
  k_conv3 <<<512,  256, 0, stream>>>(z2, wc3p, eb3, z3, z3h, z3l);
  k_vqp   <<<256,  256, 0, stream>>>(z3h, z3l, cbf, c2, idxb);
  k_vqf   <<<256,  256, 0, stream>>>(z3, cb, idxb, et, acc);
  k_convT1<<<1024, 256, 0, stream>>>(et, wt1f, db1, h1t);
  k_convT2<<<1024, 256, 0, stream>>>(h1t, wt2f, db2, h2t);
  k_convT3<<<8000, 256, 0, stream>>>(h2t, w3f, db3, x, out + 3, psum);
  k_fin   <<<1,    256, 0, stream>>>(acc, psum, out);
}